// Round 3
// baseline (831.124 us; speedup 1.0000x reference)
//
#include <hip/hip_runtime.h>

namespace {
constexpr int Bn = 2, Cin = 64, Cout = 64;
constexpr int Dd = 8, Hh = 48, Wd = 48;
constexpr int K = 27;
constexpr int SP = Dd * Hh * Wd;   // 18432
constexpr int PLANE = Hh * Wd;     // 2304
constexpr int NTILE = SP / 64;     // 288 position tiles per batch
}

// x [B,C,D,H,W] -> xT [B, spatial, C]  (channels-last for coalesced gathers)
__global__ __launch_bounds__(256) void k_xT(const float* __restrict__ x,
                                            float* __restrict__ xT) {
  int i = blockIdx.x * 256 + threadIdx.x;   // B*SP*Cin = 2,359,296
  int c = i & 63;
  int rest = i >> 6;
  int p = rest % SP;
  int b = rest / SP;
  xT[i] = x[(b * Cin + c) * SP + p];
}

// weight [co][i][k] -> wT [k][i][co]
__global__ __launch_bounds__(256) void k_wT(const float* __restrict__ w,
                                            float* __restrict__ wT) {
  int idx = blockIdx.x * 256 + threadIdx.x; // k*4096 + i*64 + co ; 110592 total
  int co = idx & 63;
  int i = (idx >> 6) & 63;
  int k = idx >> 12;
  wT[idx] = w[(co * Cin + i) * K + k];
}

// Offset conv, im2col-in-LDS. Block = 16x16 plane tile x one d x one dim group
// (27 channels). Per cin: stage 3x18x18 halo in LDS (double-buffered), then
// 27ch x 27tap FMAs with wave-uniform weight addresses (s_load, SMEM pipe).
__global__ __launch_bounds__(256, 2) void k_off2(const float* __restrict__ x,
                                                 const float* __restrict__ cw,
                                                 const float* __restrict__ cb,
                                                 float* __restrict__ off) {
  __shared__ float xt[2][972];  // [3][18][18] per buffer

  const int bid = blockIdx.x;       // ((b*8 + d)*9 + tau)*3 + g ; 432 total
  const int g = bid % 3;
  const int tau = (bid / 3) % 9;
  const int d = (bid / 27) % 8;
  const int b = bid / 216;
  const int h0 = (tau / 3) * 16, w0 = (tau % 3) * 16;
  const int t = threadIdx.x;
  const int wl = t & 15, hl = t >> 4;   // 16x16 position tile

  const float* xb = x + (size_t)b * Cin * SP;
  const float* cwg = cw + (size_t)g * 27 * 1728;  // [27 ch][64 cin][27 tap]

  float acc[27];
#pragma unroll
  for (int ch = 0; ch < 27; ++ch) acc[ch] = cb[g * 27 + ch];

  float pre[4];
  auto issue = [&](int cin) {
#pragma unroll
    for (int j = 0; j < 4; ++j) {
      int l = t + j * 256;
      float v = 0.f;
      if (l < 972) {
        int dz = l / 324, r = l - dz * 324;
        int hy = r / 18, wx = r - hy * 18;
        int dd = d + dz - 1, hh = h0 + hy - 1, ww = w0 + wx - 1;
        if (((unsigned)dd < 8u) & ((unsigned)hh < 48u) & ((unsigned)ww < 48u))
          v = xb[cin * SP + (dd * 48 + hh) * 48 + ww];
      }
      pre[j] = v;
    }
  };
  issue(0);
  int cur = 0;
  for (int cin = 0; cin < 64; ++cin) {
#pragma unroll
    for (int j = 0; j < 4; ++j) {
      int l = t + j * 256;
      if (l < 972) xt[cur][l] = pre[j];
    }
    __syncthreads();
    if (cin + 1 < 64) issue(cin + 1);   // prefetch next halo under the FMAs
    float xv[27];
#pragma unroll
    for (int kd = 0; kd < 3; ++kd)
#pragma unroll
      for (int kh = 0; kh < 3; ++kh)
#pragma unroll
        for (int kw = 0; kw < 3; ++kw)
          xv[(kd * 3 + kh) * 3 + kw] = xt[cur][(kd * 18 + hl + kh) * 18 + wl + kw];
    const float* wc = cwg + cin * 27;
#pragma unroll
    for (int ch = 0; ch < 27; ++ch) {
      const float* wr = wc + (size_t)ch * 1728;  // uniform addr -> s_load rows
#pragma unroll
      for (int tp = 0; tp < 27; ++tp)
        acc[ch] = fmaf(xv[tp], wr[tp], acc[ch]);
    }
    cur ^= 1;
  }
  // off[b][g*27+ch][d][h0+hl][w0+wl]
  size_t obase = ((size_t)b * 81 + g * 27) * SP + d * PLANE + (h0 + hl) * 48 + (w0 + wl);
#pragma unroll
  for (int ch = 0; ch < 27; ++ch) off[obase + (size_t)ch * SP] = acc[ch];
}

// Fused gather + GEMM, K-split across blocks. Block tile: 64 pos x 64 co,
// kper k-points; writes a partial [64co][64pos] tile to `part`.
// Thread GEMM tile: 4 co x 4 pos (register-blocked, b128 LDS reads only).
__global__ __launch_bounds__(256, 6) void k_mainp(const float* __restrict__ xT,
                                                  const float* __restrict__ off,
                                                  const float* __restrict__ wT,
                                                  float* __restrict__ part,
                                                  int kper) {
  __shared__ __align__(16) float vals[64 * 68];   // [cin][pos], row stride 68
  __shared__ __align__(16) unsigned scp[64 * 20]; // [pos][8 x (idx64,wgt)]

  const int t = threadIdx.x;
  const int bid = blockIdx.x;                    // kc*576 + b*288 + tile
  const int kc = bid / 576;
  const int rem = bid - kc * 576;
  const int b = rem / NTILE;
  const int tile = rem - b * NTILE;
  const int p0 = tile * 64;

  const float* xb = xT + b * SP * 64;
  const float* offb = off + b * 81 * SP;

  const int cq = t & 15;   // co = 4*cq + r
  const int pq = t >> 4;   // pos = 4*pq + q
  float4 acc[4];
#pragma unroll
  for (int r = 0; r < 4; ++r) acc[r] = float4{0.f, 0.f, 0.f, 0.f};

  for (int kk = 0; kk < kper; ++kk) {
    const int k = kc * kper + kk;
    {
      int pl = t & 63, cg = t >> 6;
      int p = p0 + pl;
      int d = p / PLANE;
      int rp = p - d * PLANE;
      int h = rp / 48;
      int w = rp - h * 48;
      int kd = k / 9, kh = (k % 9) / 3, kw2 = k % 3;
      float pd = (float)(d + kd - 1) + offb[k * SP + p];
      float ph = (float)(h + kh - 1) + offb[(27 + k) * SP + p];
      float pw = (float)(w + kw2 - 1) + offb[(54 + k) * SP + p];
      float df = floorf(pd), hf = floorf(ph), wf = floorf(pw);
      float fd = pd - df, fh = ph - hf, fw = pw - wf;
      int d0 = (int)df, h0 = (int)hf, w0i = (int)wf;
#pragma unroll
      for (int cc = 0; cc < 2; ++cc) {
        int c = cg * 2 + cc;
        int cd = c >> 2, ch = (c >> 1) & 1, cwb = c & 1;
        int di = d0 + cd, hi = h0 + ch, wi = w0i + cwb;
        bool v = ((unsigned)di < 8u) && ((unsigned)hi < 48u) && ((unsigned)wi < 48u);
        float wg = (cd ? fd : 1.f - fd) * (ch ? fh : 1.f - fh) * (cwb ? fw : 1.f - fw);
        int dic = min(max(di, 0), 7), hic = min(max(hi, 0), 47), wic = min(max(wi, 0), 47);
        int idx = (dic * 48 + hic) * 48 + wic;
        scp[pl * 20 + c * 2] = (unsigned)(idx * 64);
        scp[pl * 20 + c * 2 + 1] = __float_as_uint(v ? wg : 0.f);
      }
    }
    __syncthreads();
    {
      int co = t & 63, pg = t >> 6;
      for (int j = 0; j < 16; ++j) {
        int pl = pg * 16 + j;
        const uint4* sp4 = reinterpret_cast<const uint4*>(&scp[pl * 20]);
        uint4 q0 = sp4[0], q1 = sp4[1], q2 = sp4[2], q3 = sp4[3];
        float v = 0.f;
        v = fmaf(__uint_as_float(q0.y), xb[q0.x + co], v);
        v = fmaf(__uint_as_float(q0.w), xb[q0.z + co], v);
        v = fmaf(__uint_as_float(q1.y), xb[q1.x + co], v);
        v = fmaf(__uint_as_float(q1.w), xb[q1.z + co], v);
        v = fmaf(__uint_as_float(q2.y), xb[q2.x + co], v);
        v = fmaf(__uint_as_float(q2.w), xb[q2.z + co], v);
        v = fmaf(__uint_as_float(q3.y), xb[q3.x + co], v);
        v = fmaf(__uint_as_float(q3.w), xb[q3.z + co], v);
        vals[co * 68 + pl] = v;
      }
    }
    __syncthreads();
    {
      const float4* wk4 = reinterpret_cast<const float4*>(wT + k * 4096);
#pragma unroll 8
      for (int i = 0; i < 64; ++i) {
        float4 wv = wk4[i * 16 + cq];
        float4 vv = *reinterpret_cast<const float4*>(&vals[i * 68 + 4 * pq]);
        acc[0].x = fmaf(wv.x, vv.x, acc[0].x); acc[0].y = fmaf(wv.x, vv.y, acc[0].y);
        acc[0].z = fmaf(wv.x, vv.z, acc[0].z); acc[0].w = fmaf(wv.x, vv.w, acc[0].w);
        acc[1].x = fmaf(wv.y, vv.x, acc[1].x); acc[1].y = fmaf(wv.y, vv.y, acc[1].y);
        acc[1].z = fmaf(wv.y, vv.z, acc[1].z); acc[1].w = fmaf(wv.y, vv.w, acc[1].w);
        acc[2].x = fmaf(wv.z, vv.x, acc[2].x); acc[2].y = fmaf(wv.z, vv.y, acc[2].y);
        acc[2].z = fmaf(wv.z, vv.z, acc[2].z); acc[2].w = fmaf(wv.z, vv.w, acc[2].w);
        acc[3].x = fmaf(wv.w, vv.x, acc[3].x); acc[3].y = fmaf(wv.w, vv.y, acc[3].y);
        acc[3].z = fmaf(wv.w, vv.z, acc[3].z); acc[3].w = fmaf(wv.w, vv.w, acc[3].w);
      }
    }
    __syncthreads();
  }

  float* pp = part + ((size_t)(kc * 2 + b) * NTILE + tile) * 4096;
#pragma unroll
  for (int r = 0; r < 4; ++r) {
    *reinterpret_cast<float4*>(pp + (4 * cq + r) * 64 + 4 * pq) = acc[r];
  }
}

// out[b][co][p] = bias[co] + sum_kc part[kc][b][tile][co][pos]
__global__ __launch_bounds__(256) void k_red(const float* __restrict__ part,
                                             const float* __restrict__ bias,
                                             float* __restrict__ out,
                                             int KC) {
  int i = blockIdx.x * 256 + threadIdx.x;  // 2,359,296
  int p = i % SP;
  int co = (i / SP) & 63;
  int b = i / (SP * 64);
  int tile = p >> 6, pos = p & 63;
  size_t base = ((size_t)b * NTILE + tile) * 4096 + co * 64 + pos;
  float s = bias[co];
  for (int kc = 0; kc < KC; ++kc) s += part[base + (size_t)kc * (2 * NTILE * 4096)];
  out[i] = s;
}

extern "C" void kernel_launch(void* const* d_in, const int* in_sizes, int n_in,
                              void* d_out, int out_size, void* d_ws, size_t ws_size,
                              hipStream_t stream) {
  const float* x = (const float*)d_in[0];
  const float* cw = (const float*)d_in[1];
  const float* cb = (const float*)d_in[2];
  const float* w = (const float*)d_in[3];
  const float* bias = (const float*)d_in[4];
  float* out = (float*)d_out;

  char* ws = (char*)d_ws;
  float* off = (float*)ws;                                   // 11,943,936 B
  float* xT = (float*)(ws + 11943936);                       //  9,437,184 B
  float* wT = (float*)(ws + 11943936 + 9437184);             //    442,368 B
  float* part = (float*)(ws + 21823488);                     // KC * 9,437,184 B

  int KC = (ws_size >= 21823488ULL + 9ULL * 9437184ULL) ? 9 : 3;
  int kper = 27 / KC;

  hipLaunchKernelGGL(k_xT, dim3(9216), dim3(256), 0, stream, x, xT);
  hipLaunchKernelGGL(k_wT, dim3(432), dim3(256), 0, stream, w, wT);
  hipLaunchKernelGGL(k_off2, dim3(432), dim3(256), 0, stream, x, cw, cb, off);
  hipLaunchKernelGGL(k_mainp, dim3(KC * 576), dim3(256), 0, stream, xT, off, wT, part, kper);
  hipLaunchKernelGGL(k_red, dim3(9216), dim3(256), 0, stream, part, bias, out, KC);
}

// Round 4
// 437.259 us; speedup vs baseline: 1.9008x; 1.9008x over previous
//
#include <hip/hip_runtime.h>

namespace {
constexpr int Bn = 2, Cin = 64, Cout = 64;
constexpr int Dd = 8, Hh = 48, Wd = 48;
constexpr int K = 27;
constexpr int SP = Dd * Hh * Wd;   // 18432
constexpr int PLANE = Hh * Wd;     // 2304
constexpr int NTILE = SP / 64;     // 288 position tiles per batch
}

typedef __attribute__((ext_vector_type(8))) short short8;
typedef __attribute__((ext_vector_type(4))) float f32x4;

__device__ __forceinline__ unsigned f2bf(float f) {  // RNE float->bf16 bits
  unsigned u = __float_as_uint(f);
  return (u + 0x7fffu + ((u >> 16) & 1u)) >> 16;
}

// x [B,C,D,H,W] -> xT [B, spatial, C]  (channels-last for coalesced gathers)
__global__ __launch_bounds__(256) void k_xT(const float* __restrict__ x,
                                            float* __restrict__ xT) {
  int i = blockIdx.x * 256 + threadIdx.x;   // B*SP*Cin = 2,359,296
  int c = i & 63;
  int rest = i >> 6;
  int p = rest % SP;
  int b = rest / SP;
  xT[i] = x[(b * Cin + c) * SP + p];
}

// weight [co][i][k] -> wT [k][i][co]
__global__ __launch_bounds__(256) void k_wT(const float* __restrict__ w,
                                            float* __restrict__ wT) {
  int idx = blockIdx.x * 256 + threadIdx.x; // k*4096 + i*64 + co ; 110592 total
  int co = idx & 63;
  int i = (idx >> 6) & 63;
  int k = idx >> 12;
  wT[idx] = w[(co * Cin + i) * K + k];
}

// offset-conv weights -> wp[cin][ch(96, pad from 81)][tap(32, pad from 27)] bf16
__global__ __launch_bounds__(256) void k_offw(const float* __restrict__ cw,
                                              unsigned short* __restrict__ wp) {
  int i = blockIdx.x * 256 + threadIdx.x;   // 64*96*32 = 196,608
  int tap = i & 31;
  int ch = (i >> 5) % 96;
  int cin = i / 3072;
  float v = (ch < 81 && tap < 27) ? cw[((size_t)ch * 64 + cin) * 27 + tap] : 0.f;
  wp[i] = (unsigned short)f2bf(v);
}

// Offset conv as implicit-im2col MFMA GEMM: D[96 ch][64 pos] += A[96][32] * B[32][64]
// per cin. Block = 64 positions (one 64-aligned spatial chunk), 4 waves; wave w
// owns the 16-pos column w and all 6 M-tiles. A-frags read straight from L2.
__global__ __launch_bounds__(256) void k_offm(const float* __restrict__ x,
                                              const unsigned short* __restrict__ wp,
                                              const float* __restrict__ cb,
                                              float* __restrict__ off) {
  __shared__ unsigned short bt[64 * 40];  // [pos][tap], row stride 40 (80B)

  const int t = threadIdx.x;
  const int lane = t & 63;
  const int wv = t >> 6;
  const int n0 = blockIdx.x * 64;          // 576 blocks over B*SP
  const int b = n0 / SP;
  const int sp0 = n0 - b * SP;

  // per-thread B-load setup: pos = lane, taps wv*8 .. wv*8+7 (fixed all K-steps)
  int n = sp0 + lane;
  int d = n / PLANE;
  int r = n - d * PLANE;
  int h = r / 48;
  int w = r - h * 48;
  int ofs[8], msk[8];
#pragma unroll
  for (int j = 0; j < 8; ++j) {
    int tap = wv * 8 + j;
    int kd = tap / 9, kh2 = (tap - kd * 9) / 3, kw2 = tap - kd * 9 - kh2 * 3;
    int dd = d + kd - 1, hh = h + kh2 - 1, ww = w + kw2 - 1;
    bool v = (tap < 27) && ((unsigned)dd < 8u) && ((unsigned)hh < 48u) &&
             ((unsigned)ww < 48u);
    ofs[j] = v ? ((dd * 48 + hh) * 48 + ww) : 0;
    msk[j] = v ? -1 : 0;
  }
  const float* xb = x + (size_t)b * Cin * SP;
  const int arow = lane & 15, ak = (lane >> 4) * 8;

  f32x4 acc[6];
#pragma unroll
  for (int mt = 0; mt < 6; ++mt) acc[mt] = f32x4{0.f, 0.f, 0.f, 0.f};

  float pre[8];
#pragma unroll
  for (int j = 0; j < 8; ++j) pre[j] = xb[ofs[j]];

  for (int cin = 0; cin < 64; ++cin) {
    unsigned pk[4];
#pragma unroll
    for (int q = 0; q < 4; ++q) {
      float lo = msk[2 * q] ? pre[2 * q] : 0.f;
      float hi = msk[2 * q + 1] ? pre[2 * q + 1] : 0.f;
      pk[q] = (f2bf(hi) << 16) | f2bf(lo);
    }
    __syncthreads();  // previous iteration's B-frag reads complete
    *reinterpret_cast<uint4*>(&bt[lane * 40 + wv * 8]) =
        uint4{pk[0], pk[1], pk[2], pk[3]};
    __syncthreads();
    if (cin < 63) {   // prefetch next cin's B values (lands under MFMA phase)
      const float* xn = xb + (size_t)(cin + 1) * SP;
#pragma unroll
      for (int j = 0; j < 8; ++j) pre[j] = xn[ofs[j]];
    }
    // A-frags from L2 (same addresses across all blocks)
    const unsigned short* wa = wp + (size_t)cin * 3072 + arow * 32 + ak;
    short8 af[6];
#pragma unroll
    for (int mt = 0; mt < 6; ++mt)
      af[mt] = *reinterpret_cast<const short8*>(wa + mt * 512);
    short8 bf = *reinterpret_cast<const short8*>(&bt[(wv * 16 + arow) * 40 + ak]);
#pragma unroll
    for (int mt = 0; mt < 6; ++mt)
      acc[mt] = __builtin_amdgcn_mfma_f32_16x16x32_bf16(af[mt], bf, acc[mt], 0, 0, 0);
  }

  // D: col = lane&15 (pos), row = (lane>>4)*4 + reg (ch within 16-tile)
  int colp = sp0 + wv * 16 + (lane & 15);
#pragma unroll
  for (int mt = 0; mt < 6; ++mt) {
#pragma unroll
    for (int reg = 0; reg < 4; ++reg) {
      int ch = mt * 16 + (lane >> 4) * 4 + reg;
      if (ch < 81)
        off[((size_t)b * 81 + ch) * SP + colp] = acc[mt][reg] + cb[ch];
    }
  }
}

// Fused gather + GEMM, K-split across blocks. Block tile: 64 pos x 64 co,
// kper k-points; writes a partial [64co][64pos] tile to `part`.
__global__ __launch_bounds__(256, 6) void k_mainp(const float* __restrict__ xT,
                                                  const float* __restrict__ off,
                                                  const float* __restrict__ wT,
                                                  float* __restrict__ part,
                                                  int kper) {
  __shared__ __align__(16) float vals[64 * 68];   // [cin][pos], row stride 68
  __shared__ __align__(16) unsigned scp[64 * 20]; // [pos][8 x (idx64,wgt)]

  const int t = threadIdx.x;
  const int bid = blockIdx.x;                    // kc*576 + b*288 + tile
  const int kc = bid / 576;
  const int rem = bid - kc * 576;
  const int b = rem / NTILE;
  const int tile = rem - b * NTILE;
  const int p0 = tile * 64;

  const float* xb = xT + b * SP * 64;
  const float* offb = off + b * 81 * SP;

  const int cq = t & 15;   // co = 4*cq + r
  const int pq = t >> 4;   // pos = 4*pq + q
  float4 acc[4];
#pragma unroll
  for (int r = 0; r < 4; ++r) acc[r] = float4{0.f, 0.f, 0.f, 0.f};

  for (int kk = 0; kk < kper; ++kk) {
    const int k = kc * kper + kk;
    {
      int pl = t & 63, cg = t >> 6;
      int p = p0 + pl;
      int d = p / PLANE;
      int rp = p - d * PLANE;
      int h = rp / 48;
      int w = rp - h * 48;
      int kd = k / 9, kh = (k % 9) / 3, kw2 = k % 3;
      float pd = (float)(d + kd - 1) + offb[k * SP + p];
      float ph = (float)(h + kh - 1) + offb[(27 + k) * SP + p];
      float pw = (float)(w + kw2 - 1) + offb[(54 + k) * SP + p];
      float df = floorf(pd), hf = floorf(ph), wf = floorf(pw);
      float fd = pd - df, fh = ph - hf, fw = pw - wf;
      int d0 = (int)df, h0 = (int)hf, w0i = (int)wf;
#pragma unroll
      for (int cc = 0; cc < 2; ++cc) {
        int c = cg * 2 + cc;
        int cd = c >> 2, ch = (c >> 1) & 1, cwb = c & 1;
        int di = d0 + cd, hi = h0 + ch, wi = w0i + cwb;
        bool v = ((unsigned)di < 8u) && ((unsigned)hi < 48u) && ((unsigned)wi < 48u);
        float wg = (cd ? fd : 1.f - fd) * (ch ? fh : 1.f - fh) * (cwb ? fw : 1.f - fw);
        int dic = min(max(di, 0), 7), hic = min(max(hi, 0), 47), wic = min(max(wi, 0), 47);
        int idx = (dic * 48 + hic) * 48 + wic;
        scp[pl * 20 + c * 2] = (unsigned)(idx * 64);
        scp[pl * 20 + c * 2 + 1] = __float_as_uint(v ? wg : 0.f);
      }
    }
    __syncthreads();
    {
      int co = t & 63, pg = t >> 6;
      for (int j = 0; j < 16; ++j) {
        int pl = pg * 16 + j;
        const uint4* sp4 = reinterpret_cast<const uint4*>(&scp[pl * 20]);
        uint4 q0 = sp4[0], q1 = sp4[1], q2 = sp4[2], q3 = sp4[3];
        float v = 0.f;
        v = fmaf(__uint_as_float(q0.y), xb[q0.x + co], v);
        v = fmaf(__uint_as_float(q0.w), xb[q0.z + co], v);
        v = fmaf(__uint_as_float(q1.y), xb[q1.x + co], v);
        v = fmaf(__uint_as_float(q1.w), xb[q1.z + co], v);
        v = fmaf(__uint_as_float(q2.y), xb[q2.x + co], v);
        v = fmaf(__uint_as_float(q2.w), xb[q2.z + co], v);
        v = fmaf(__uint_as_float(q3.y), xb[q3.x + co], v);
        v = fmaf(__uint_as_float(q3.w), xb[q3.z + co], v);
        vals[co * 68 + pl] = v;
      }
    }
    __syncthreads();
    {
      const float4* wk4 = reinterpret_cast<const float4*>(wT + k * 4096);
#pragma unroll 8
      for (int i = 0; i < 64; ++i) {
        float4 wv = wk4[i * 16 + cq];
        float4 vv = *reinterpret_cast<const float4*>(&vals[i * 68 + 4 * pq]);
        acc[0].x = fmaf(wv.x, vv.x, acc[0].x); acc[0].y = fmaf(wv.x, vv.y, acc[0].y);
        acc[0].z = fmaf(wv.x, vv.z, acc[0].z); acc[0].w = fmaf(wv.x, vv.w, acc[0].w);
        acc[1].x = fmaf(wv.y, vv.x, acc[1].x); acc[1].y = fmaf(wv.y, vv.y, acc[1].y);
        acc[1].z = fmaf(wv.y, vv.z, acc[1].z); acc[1].w = fmaf(wv.y, vv.w, acc[1].w);
        acc[2].x = fmaf(wv.z, vv.x, acc[2].x); acc[2].y = fmaf(wv.z, vv.y, acc[2].y);
        acc[2].z = fmaf(wv.z, vv.z, acc[2].z); acc[2].w = fmaf(wv.z, vv.w, acc[2].w);
        acc[3].x = fmaf(wv.w, vv.x, acc[3].x); acc[3].y = fmaf(wv.w, vv.y, acc[3].y);
        acc[3].z = fmaf(wv.w, vv.z, acc[3].z); acc[3].w = fmaf(wv.w, vv.w, acc[3].w);
      }
    }
    __syncthreads();
  }

  float* pp = part + ((size_t)(kc * 2 + b) * NTILE + tile) * 4096;
#pragma unroll
  for (int r = 0; r < 4; ++r) {
    *reinterpret_cast<float4*>(pp + (4 * cq + r) * 64 + 4 * pq) = acc[r];
  }
}

// out[b][co][p] = bias[co] + sum_kc part[kc][b][tile][co][pos]
__global__ __launch_bounds__(256) void k_red(const float* __restrict__ part,
                                             const float* __restrict__ bias,
                                             float* __restrict__ out,
                                             int KC) {
  int i = blockIdx.x * 256 + threadIdx.x;  // 2,359,296
  int p = i % SP;
  int co = (i / SP) & 63;
  int b = i / (SP * 64);
  int tile = p >> 6, pos = p & 63;
  size_t base = ((size_t)b * NTILE + tile) * 4096 + co * 64 + pos;
  float s = bias[co];
  for (int kc = 0; kc < KC; ++kc) s += part[base + (size_t)kc * (2 * NTILE * 4096)];
  out[i] = s;
}

extern "C" void kernel_launch(void* const* d_in, const int* in_sizes, int n_in,
                              void* d_out, int out_size, void* d_ws, size_t ws_size,
                              hipStream_t stream) {
  const float* x = (const float*)d_in[0];
  const float* cw = (const float*)d_in[1];
  const float* cb = (const float*)d_in[2];
  const float* w = (const float*)d_in[3];
  const float* bias = (const float*)d_in[4];
  float* out = (float*)d_out;

  char* ws = (char*)d_ws;
  float* off = (float*)ws;                                   // 11,943,936 B
  float* xT = (float*)(ws + 11943936);                       //  9,437,184 B
  float* wT = (float*)(ws + 11943936 + 9437184);             //    442,368 B
  unsigned short* wp = (unsigned short*)(ws + 21823488);     //    393,216 B
  float* part = (float*)(ws + 22216704);                     // KC * 9,437,184 B

  int KC = (ws_size >= 22216704ULL + 9ULL * 9437184ULL) ? 9 : 3;
  int kper = 27 / KC;

  hipLaunchKernelGGL(k_xT, dim3(9216), dim3(256), 0, stream, x, xT);
  hipLaunchKernelGGL(k_wT, dim3(432), dim3(256), 0, stream, w, wT);
  hipLaunchKernelGGL(k_offw, dim3(768), dim3(256), 0, stream, cw, wp);
  hipLaunchKernelGGL(k_offm, dim3(576), dim3(256), 0, stream, x, wp, cb, off);
  hipLaunchKernelGGL(k_mainp, dim3(576 * 9 / (27 / 3) * 0 + 576 * ((ws_size >= 22216704ULL + 9ULL * 9437184ULL) ? 9 : 3)), dim3(256), 0, stream, xT, off, wT, part, kper);
  hipLaunchKernelGGL(k_red, dim3(9216), dim3(256), 0, stream, part, bias, out, KC);
}

// Round 5
// 249.127 us; speedup vs baseline: 3.3361x; 1.7552x over previous
//
#include <hip/hip_runtime.h>

namespace {
constexpr int Bn = 2, Cin = 64, Cout = 64;
constexpr int Dd = 8, Hh = 48, Wd = 48;
constexpr int K = 27;
constexpr int SP = Dd * Hh * Wd;   // 18432
constexpr int PLANE = Hh * Wd;     // 2304
constexpr int NTILE = SP / 64;     // 288 position tiles per batch
}

typedef __attribute__((ext_vector_type(8))) short short8;
typedef __attribute__((ext_vector_type(4))) float f32x4;

__device__ __forceinline__ unsigned f2bf(float f) {  // RNE float->bf16 bits
  unsigned u = __float_as_uint(f);
  return (u + 0x7fffu + ((u >> 16) & 1u)) >> 16;
}
__device__ __forceinline__ float bf2f(unsigned short h) {
  return __uint_as_float(((unsigned)h) << 16);
}

// x [B,C,D,H,W] -> xTh [B, spatial, C] bf16 (channels-last, halves gather bytes)
__global__ __launch_bounds__(256) void k_xTh(const float* __restrict__ x,
                                             unsigned short* __restrict__ xTh) {
  int i = blockIdx.x * 256 + threadIdx.x;   // B*SP*Cin = 2,359,296
  int c = i & 63;
  int rest = i >> 6;
  int p = rest % SP;
  int b = rest / SP;
  xTh[i] = (unsigned short)f2bf(x[(b * Cin + c) * SP + p]);
}

// main weights -> per-lane-contiguous MFMA A-frag layout, bf16:
// wTb[k][mt(4)][s(2)][row(16)][kg(4)][j(8)] ; co = mt*16+row, cin = s*32+kg*8+j
__global__ __launch_bounds__(256) void k_wTb(const float* __restrict__ w,
                                             unsigned short* __restrict__ wTb) {
  int i = blockIdx.x * 256 + threadIdx.x;   // 27*4096 = 110,592
  int j = i & 7, kg = (i >> 3) & 3, row = (i >> 5) & 15;
  int s = (i >> 9) & 1, mt = (i >> 10) & 3, k = i >> 12;
  int co = mt * 16 + row, cin = s * 32 + kg * 8 + j;
  wTb[i] = (unsigned short)f2bf(w[((size_t)co * Cin + cin) * K + k]);
}

// offset-conv weights -> wp[cin][ch(96, pad from 81)][tap(32, pad from 27)] bf16
__global__ __launch_bounds__(256) void k_offw(const float* __restrict__ cw,
                                              unsigned short* __restrict__ wp) {
  int i = blockIdx.x * 256 + threadIdx.x;   // 64*96*32 = 196,608
  int tap = i & 31;
  int ch = (i >> 5) % 96;
  int cin = i / 3072;
  float v = (ch < 81 && tap < 27) ? cw[((size_t)ch * 64 + cin) * 27 + tap] : 0.f;
  wp[i] = (unsigned short)f2bf(v);
}

// Offset conv as implicit-im2col MFMA GEMM (validated round 4).
__global__ __launch_bounds__(256) void k_offm(const float* __restrict__ x,
                                              const unsigned short* __restrict__ wp,
                                              const float* __restrict__ cb,
                                              float* __restrict__ off) {
  __shared__ unsigned short bt[64 * 40];  // [pos][tap], row stride 40 (80B)

  const int t = threadIdx.x;
  const int lane = t & 63;
  const int wv = t >> 6;
  const int n0 = blockIdx.x * 64;          // 576 blocks over B*SP
  const int b = n0 / SP;
  const int sp0 = n0 - b * SP;

  int n = sp0 + lane;
  int d = n / PLANE;
  int r = n - d * PLANE;
  int h = r / 48;
  int w = r - h * 48;
  int ofs[8], msk[8];
#pragma unroll
  for (int j = 0; j < 8; ++j) {
    int tap = wv * 8 + j;
    int kd = tap / 9, kh2 = (tap - kd * 9) / 3, kw2 = tap - kd * 9 - kh2 * 3;
    int dd = d + kd - 1, hh = h + kh2 - 1, ww = w + kw2 - 1;
    bool v = (tap < 27) && ((unsigned)dd < 8u) && ((unsigned)hh < 48u) &&
             ((unsigned)ww < 48u);
    ofs[j] = v ? ((dd * 48 + hh) * 48 + ww) : 0;
    msk[j] = v ? -1 : 0;
  }
  const float* xb = x + (size_t)b * Cin * SP;
  const int arow = lane & 15, ak = (lane >> 4) * 8;

  f32x4 acc[6];
#pragma unroll
  for (int mt = 0; mt < 6; ++mt) acc[mt] = f32x4{0.f, 0.f, 0.f, 0.f};

  float pre[8];
#pragma unroll
  for (int j = 0; j < 8; ++j) pre[j] = xb[ofs[j]];

  for (int cin = 0; cin < 64; ++cin) {
    unsigned pk[4];
#pragma unroll
    for (int q = 0; q < 4; ++q) {
      float lo = msk[2 * q] ? pre[2 * q] : 0.f;
      float hi = msk[2 * q + 1] ? pre[2 * q + 1] : 0.f;
      pk[q] = (f2bf(hi) << 16) | f2bf(lo);
    }
    __syncthreads();
    *reinterpret_cast<uint4*>(&bt[lane * 40 + wv * 8]) =
        uint4{pk[0], pk[1], pk[2], pk[3]};
    __syncthreads();
    if (cin < 63) {
      const float* xn = xb + (size_t)(cin + 1) * SP;
#pragma unroll
      for (int j = 0; j < 8; ++j) pre[j] = xn[ofs[j]];
    }
    const unsigned short* wa = wp + (size_t)cin * 3072 + arow * 32 + ak;
    short8 af[6];
#pragma unroll
    for (int mt = 0; mt < 6; ++mt)
      af[mt] = *reinterpret_cast<const short8*>(wa + mt * 512);
    short8 bf = *reinterpret_cast<const short8*>(&bt[(wv * 16 + arow) * 40 + ak]);
#pragma unroll
    for (int mt = 0; mt < 6; ++mt)
      acc[mt] = __builtin_amdgcn_mfma_f32_16x16x32_bf16(af[mt], bf, acc[mt], 0, 0, 0);
  }

  int colp = sp0 + wv * 16 + (lane & 15);
#pragma unroll
  for (int mt = 0; mt < 6; ++mt) {
#pragma unroll
    for (int reg = 0; reg < 4; ++reg) {
      int ch = mt * 16 + (lane >> 4) * 4 + reg;
      if (ch < 81)
        off[((size_t)b * 81 + ch) * SP + colp] = acc[mt][reg] + cb[ch];
    }
  }
}

// Fused gather + MFMA GEMM, K-split across blocks. Block tile: 64 pos x 64 co.
// XCD-aware tile swizzle: blockIdx%8 (=XCD) owns 72 contiguous tiles so the
// gather footprint (~1.2 MB bf16 + halo) fits that XCD's 4 MB L2.
__global__ __launch_bounds__(256, 6) void k_mainp(const unsigned short* __restrict__ xTh,
                                                  const float* __restrict__ off,
                                                  const unsigned short* __restrict__ wTb,
                                                  float* __restrict__ part,
                                                  int kper) {
  __shared__ __align__(16) unsigned short vals[64 * 72]; // [pos][cin] bf16, stride 144 B
  __shared__ __align__(16) unsigned scp[64 * 20];        // [pos][8 x (idx64,wgt)]

  const int t = threadIdx.x;
  const int bid = blockIdx.x;                    // kc*576 + j
  const int kc = bid / 576;
  const int j = bid - kc * 576;
  const int tl = (j & 7) * 72 + (j >> 3);        // XCD-contiguous tile blocks
  const int b = tl / NTILE;
  const int tile = tl - b * NTILE;
  const int p0 = tile * 64;

  const unsigned short* xh = xTh + (size_t)b * SP * 64;
  const float* offb = off + (size_t)b * 81 * SP;

  const int lane = t & 63;
  const int wv = t >> 6;

  f32x4 acc[4];
#pragma unroll
  for (int mt = 0; mt < 4; ++mt) acc[mt] = f32x4{0.f, 0.f, 0.f, 0.f};

  for (int kk = 0; kk < kper; ++kk) {
    const int k = kc * kper + kk;
    // ---- corner setup: pl = t&63, cg = t>>6 computes corners 2cg, 2cg+1
    {
      int pl = lane, cg = wv;
      int p = p0 + pl;
      int d = p / PLANE;
      int rp = p - d * PLANE;
      int h = rp / 48;
      int w = rp - h * 48;
      int kd = k / 9, kh = (k % 9) / 3, kw2 = k % 3;
      float pd = (float)(d + kd - 1) + offb[k * SP + p];
      float ph = (float)(h + kh - 1) + offb[(27 + k) * SP + p];
      float pw = (float)(w + kw2 - 1) + offb[(54 + k) * SP + p];
      float df = floorf(pd), hf = floorf(ph), wf = floorf(pw);
      float fd = pd - df, fh = ph - hf, fw = pw - wf;
      int d0 = (int)df, h0 = (int)hf, w0i = (int)wf;
#pragma unroll
      for (int cc = 0; cc < 2; ++cc) {
        int c = cg * 2 + cc;
        int cd = c >> 2, ch = (c >> 1) & 1, cwb = c & 1;
        int di = d0 + cd, hi = h0 + ch, wi = w0i + cwb;
        bool v = ((unsigned)di < 8u) && ((unsigned)hi < 48u) && ((unsigned)wi < 48u);
        float wg = (cd ? fd : 1.f - fd) * (ch ? fh : 1.f - fh) * (cwb ? fw : 1.f - fw);
        int dic = min(max(di, 0), 7), hic = min(max(hi, 0), 47), wic = min(max(wi, 0), 47);
        int idx = (dic * 48 + hic) * 48 + wic;
        scp[pl * 20 + c * 2] = (unsigned)(idx * 64);
        scp[pl * 20 + c * 2 + 1] = __float_as_uint(v ? wg : 0.f);
      }
    }
    __syncthreads();
    // ---- gather: lane = cin, 16 positions per wave-row, bf16 into vals[pos][cin]
    {
      int ci = lane;
      for (int jj = 0; jj < 16; ++jj) {
        int pl = wv * 16 + jj;
        const uint4* sp4 = reinterpret_cast<const uint4*>(&scp[pl * 20]);
        uint4 q0 = sp4[0], q1 = sp4[1], q2 = sp4[2], q3 = sp4[3];
        float v = 0.f;
        v = fmaf(__uint_as_float(q0.y), bf2f(xh[q0.x + ci]), v);
        v = fmaf(__uint_as_float(q0.w), bf2f(xh[q0.z + ci]), v);
        v = fmaf(__uint_as_float(q1.y), bf2f(xh[q1.x + ci]), v);
        v = fmaf(__uint_as_float(q1.w), bf2f(xh[q1.z + ci]), v);
        v = fmaf(__uint_as_float(q2.y), bf2f(xh[q2.x + ci]), v);
        v = fmaf(__uint_as_float(q2.w), bf2f(xh[q2.z + ci]), v);
        v = fmaf(__uint_as_float(q3.y), bf2f(xh[q3.x + ci]), v);
        v = fmaf(__uint_as_float(q3.w), bf2f(xh[q3.z + ci]), v);
        vals[pl * 72 + ci] = (unsigned short)f2bf(v);
      }
    }
    __syncthreads();
    // ---- MFMA: C[co][pos] += W[co][cin] * V[cin][pos]; A from L2, B from LDS
    {
      const unsigned short* wk = wTb + (size_t)k * 4096;
#pragma unroll
      for (int s = 0; s < 2; ++s) {
        short8 bfr = *reinterpret_cast<const short8*>(
            &vals[(wv * 16 + (lane & 15)) * 72 + s * 32 + (lane >> 4) * 8]);
#pragma unroll
        for (int mt = 0; mt < 4; ++mt) {
          short8 afr = *reinterpret_cast<const short8*>(
              wk + mt * 1024 + s * 512 + (lane & 15) * 32 + (lane >> 4) * 8);
          acc[mt] = __builtin_amdgcn_mfma_f32_16x16x32_bf16(afr, bfr, acc[mt], 0, 0, 0);
        }
      }
    }
    __syncthreads();
  }

  // part[kc][b][tile][co][pos]; co = mt*16+(lane>>4)*4+reg, pos = wv*16+(lane&15)
  float* pp = part + ((size_t)(kc * 2 + b) * NTILE + tile) * 4096;
#pragma unroll
  for (int mt = 0; mt < 4; ++mt) {
#pragma unroll
    for (int reg = 0; reg < 4; ++reg) {
      int co = mt * 16 + (lane >> 4) * 4 + reg;
      pp[co * 64 + wv * 16 + (lane & 15)] = acc[mt][reg];
    }
  }
}

// out[b][co][p] = bias[co] + sum_kc part[kc][b][tile][co][pos]
__global__ __launch_bounds__(256) void k_red(const float* __restrict__ part,
                                             const float* __restrict__ bias,
                                             float* __restrict__ out,
                                             int KC) {
  int i = blockIdx.x * 256 + threadIdx.x;  // 2,359,296
  int p = i % SP;
  int co = (i / SP) & 63;
  int b = i / (SP * 64);
  int tile = p >> 6, pos = p & 63;
  size_t base = ((size_t)b * NTILE + tile) * 4096 + co * 64 + pos;
  float s = bias[co];
  for (int kc = 0; kc < KC; ++kc) s += part[base + (size_t)kc * (2 * NTILE * 4096)];
  out[i] = s;
}

extern "C" void kernel_launch(void* const* d_in, const int* in_sizes, int n_in,
                              void* d_out, int out_size, void* d_ws, size_t ws_size,
                              hipStream_t stream) {
  const float* x = (const float*)d_in[0];
  const float* cw = (const float*)d_in[1];
  const float* cb = (const float*)d_in[2];
  const float* w = (const float*)d_in[3];
  const float* bias = (const float*)d_in[4];
  float* out = (float*)d_out;

  char* ws = (char*)d_ws;
  float* off = (float*)ws;                                   // 11,943,936 B
  unsigned short* xTh = (unsigned short*)(ws + 11943936);    //  4,718,592 B
  unsigned short* wTb = (unsigned short*)(ws + 16662528);    //    221,184 B
  unsigned short* wp = (unsigned short*)(ws + 16883712);     //    393,216 B
  float* part = (float*)(ws + 17276928);                     // KC * 9,437,184 B

  int KC = (ws_size >= 17276928ULL + 9ULL * 9437184ULL) ? 9 : 3;
  int kper = 27 / KC;

  hipLaunchKernelGGL(k_xTh, dim3(9216), dim3(256), 0, stream, x, xTh);
  hipLaunchKernelGGL(k_wTb, dim3(432), dim3(256), 0, stream, w, wTb);
  hipLaunchKernelGGL(k_offw, dim3(768), dim3(256), 0, stream, cw, wp);
  hipLaunchKernelGGL(k_offm, dim3(576), dim3(256), 0, stream, x, wp, cb, off);
  hipLaunchKernelGGL(k_mainp, dim3(KC * 576), dim3(256), 0, stream, xTh, off, wTb, part, kper);
  hipLaunchKernelGGL(k_red, dim3(9216), dim3(256), 0, stream, part, bias, out, KC);
}

// Round 6
// 192.788 us; speedup vs baseline: 4.3111x; 1.2922x over previous
//
#include <hip/hip_runtime.h>

namespace {
constexpr int Bn = 2, Cin = 64, Cout = 64;
constexpr int Dd = 8, Hh = 48, Wd = 48;
constexpr int K = 27;
constexpr int SP = Dd * Hh * Wd;   // 18432
constexpr int PLANE = Hh * Wd;     // 2304
constexpr int NTILE = SP / 64;     // 288 position tiles per batch
constexpr int KC = 3;              // K-split factor
constexpr int KPER = K / KC;       // 9
}

typedef __attribute__((ext_vector_type(8))) short short8;
typedef __attribute__((ext_vector_type(4))) float f32x4;

__device__ __forceinline__ unsigned f2bf(float f) {  // RNE float->bf16 bits
  unsigned u = __float_as_uint(f);
  return (u + 0x7fffu + ((u >> 16) & 1u)) >> 16;
}

// x [B,C,D,H,W] -> xTh [B, spatial, C] bf16 (channels-last, halves gather bytes)
__global__ __launch_bounds__(256) void k_xTh(const float* __restrict__ x,
                                             unsigned short* __restrict__ xTh) {
  int i = blockIdx.x * 256 + threadIdx.x;   // B*SP*Cin = 2,359,296
  int c = i & 63;
  int rest = i >> 6;
  int p = rest % SP;
  int b = rest / SP;
  xTh[i] = (unsigned short)f2bf(x[(b * Cin + c) * SP + p]);
}

// main weights -> per-lane-contiguous MFMA A-frag layout, bf16:
// wTb[k][mt(4)][s(2)][row(16)][kg(4)][j(8)] ; co = mt*16+row, cin = s*32+kg*8+j
__global__ __launch_bounds__(256) void k_wTb(const float* __restrict__ w,
                                             unsigned short* __restrict__ wTb) {
  int i = blockIdx.x * 256 + threadIdx.x;   // 27*4096 = 110,592
  int j = i & 7, kg = (i >> 3) & 3, row = (i >> 5) & 15;
  int s = (i >> 9) & 1, mt = (i >> 10) & 3, k = i >> 12;
  int co = mt * 16 + row, cin = s * 32 + kg * 8 + j;
  wTb[i] = (unsigned short)f2bf(w[((size_t)co * Cin + cin) * K + k]);
}

// offset-conv weights -> wp[cin][ch(96, pad from 81)][tap(32, pad from 27)] bf16
__global__ __launch_bounds__(256) void k_offw(const float* __restrict__ cw,
                                              unsigned short* __restrict__ wp) {
  int i = blockIdx.x * 256 + threadIdx.x;   // 64*96*32 = 196,608
  int tap = i & 31;
  int ch = (i >> 5) % 96;
  int cin = i / 3072;
  float v = (ch < 81 && tap < 27) ? cw[((size_t)ch * 64 + cin) * 27 + tap] : 0.f;
  wp[i] = (unsigned short)f2bf(v);
}

// Offset conv as implicit-im2col MFMA GEMM (validated round 4).
__global__ __launch_bounds__(256) void k_offm(const float* __restrict__ x,
                                              const unsigned short* __restrict__ wp,
                                              const float* __restrict__ cb,
                                              float* __restrict__ off) {
  __shared__ unsigned short bt[64 * 40];  // [pos][tap], row stride 40 (80B)

  const int t = threadIdx.x;
  const int lane = t & 63;
  const int wv = t >> 6;
  const int n0 = blockIdx.x * 64;          // 576 blocks over B*SP
  const int b = n0 / SP;
  const int sp0 = n0 - b * SP;

  int n = sp0 + lane;
  int d = n / PLANE;
  int r = n - d * PLANE;
  int h = r / 48;
  int w = r - h * 48;
  int ofs[8], msk[8];
#pragma unroll
  for (int j = 0; j < 8; ++j) {
    int tap = wv * 8 + j;
    int kd = tap / 9, kh2 = (tap - kd * 9) / 3, kw2 = tap - kd * 9 - kh2 * 3;
    int dd = d + kd - 1, hh = h + kh2 - 1, ww = w + kw2 - 1;
    bool v = (tap < 27) && ((unsigned)dd < 8u) && ((unsigned)hh < 48u) &&
             ((unsigned)ww < 48u);
    ofs[j] = v ? ((dd * 48 + hh) * 48 + ww) : 0;
    msk[j] = v ? -1 : 0;
  }
  const float* xb = x + (size_t)b * Cin * SP;
  const int arow = lane & 15, ak = (lane >> 4) * 8;

  f32x4 acc[6];
#pragma unroll
  for (int mt = 0; mt < 6; ++mt) acc[mt] = f32x4{0.f, 0.f, 0.f, 0.f};

  float pre[8];
#pragma unroll
  for (int j = 0; j < 8; ++j) pre[j] = xb[ofs[j]];

  for (int cin = 0; cin < 64; ++cin) {
    unsigned pk[4];
#pragma unroll
    for (int q = 0; q < 4; ++q) {
      float lo = msk[2 * q] ? pre[2 * q] : 0.f;
      float hi = msk[2 * q + 1] ? pre[2 * q + 1] : 0.f;
      pk[q] = (f2bf(hi) << 16) | f2bf(lo);
    }
    __syncthreads();
    *reinterpret_cast<uint4*>(&bt[lane * 40 + wv * 8]) =
        uint4{pk[0], pk[1], pk[2], pk[3]};
    __syncthreads();
    if (cin < 63) {
      const float* xn = xb + (size_t)(cin + 1) * SP;
#pragma unroll
      for (int j = 0; j < 8; ++j) pre[j] = xn[ofs[j]];
    }
    const unsigned short* wa = wp + (size_t)cin * 3072 + arow * 32 + ak;
    short8 af[6];
#pragma unroll
    for (int mt = 0; mt < 6; ++mt)
      af[mt] = *reinterpret_cast<const short8*>(wa + mt * 512);
    short8 bf = *reinterpret_cast<const short8*>(&bt[(wv * 16 + arow) * 40 + ak]);
#pragma unroll
    for (int mt = 0; mt < 6; ++mt)
      acc[mt] = __builtin_amdgcn_mfma_f32_16x16x32_bf16(af[mt], bf, acc[mt], 0, 0, 0);
  }

  int colp = sp0 + wv * 16 + (lane & 15);
#pragma unroll
  for (int mt = 0; mt < 6; ++mt) {
#pragma unroll
    for (int reg = 0; reg < 4; ++reg) {
      int ch = mt * 16 + (lane >> 4) * 4 + reg;
      if (ch < 81)
        off[((size_t)b * 81 + ch) * SP + colp] = acc[mt][reg] + cb[ch];
    }
  }
}

__device__ __forceinline__ void bfma8(float* a, uint4 q, float wg) {
  unsigned u[4] = {q.x, q.y, q.z, q.w};
#pragma unroll
  for (int i = 0; i < 4; ++i) {
    float lo = __uint_as_float(u[i] << 16);
    float hi = __uint_as_float(u[i] & 0xffff0000u);
    a[2 * i] = fmaf(wg, lo, a[2 * i]);
    a[2 * i + 1] = fmaf(wg, hi, a[2 * i + 1]);
  }
}

// Fused gather + MFMA GEMM, K-split across blocks. Block tile: 64 pos x 64 co.
// XCD-aware tile swizzle; gather vectorized: 8 lanes share a position, each
// lane loads one 8-channel bf16 chunk (dwordx4) per corner.
__global__ __launch_bounds__(256, 6) void k_mainp(const unsigned short* __restrict__ xTh,
                                                  const float* __restrict__ off,
                                                  const unsigned short* __restrict__ wTb,
                                                  float* __restrict__ part) {
  __shared__ __align__(16) unsigned short vals[64 * 72]; // [pos][cin] bf16, stride 144 B
  __shared__ __align__(16) unsigned scp[64 * 20];        // [pos][8 x (idx,wgt)]

  const int t = threadIdx.x;
  const int bid = blockIdx.x;                    // kc*576 + j
  const int kc = bid / 576;
  const int j = bid - kc * 576;
  const int tl = (j & 7) * 72 + (j >> 3);        // XCD-contiguous tile blocks
  const int b = tl / NTILE;
  const int tile = tl - b * NTILE;
  const int p0 = tile * 64;

  const char* xb8 = (const char*)(xTh + (size_t)b * SP * 64);
  const float* offb = off + (size_t)b * 81 * SP;

  const int lane = t & 63;
  const int wv = t >> 6;

  f32x4 acc[4];
#pragma unroll
  for (int mt = 0; mt < 4; ++mt) acc[mt] = f32x4{0.f, 0.f, 0.f, 0.f};

  for (int kk = 0; kk < KPER; ++kk) {
    const int k = kc * KPER + kk;
    // ---- corner setup: pl = t&63, cg = t>>6 computes corners 2cg, 2cg+1
    {
      int pl = lane, cg = wv;
      int p = p0 + pl;
      int d = p / PLANE;
      int rp = p - d * PLANE;
      int h = rp / 48;
      int w = rp - h * 48;
      int kd = k / 9, kh = (k % 9) / 3, kw2 = k % 3;
      float pd = (float)(d + kd - 1) + offb[k * SP + p];
      float ph = (float)(h + kh - 1) + offb[(27 + k) * SP + p];
      float pw = (float)(w + kw2 - 1) + offb[(54 + k) * SP + p];
      float df = floorf(pd), hf = floorf(ph), wf = floorf(pw);
      float fd = pd - df, fh = ph - hf, fw = pw - wf;
      int d0 = (int)df, h0 = (int)hf, w0i = (int)wf;
#pragma unroll
      for (int cc = 0; cc < 2; ++cc) {
        int c = cg * 2 + cc;
        int cd = c >> 2, ch = (c >> 1) & 1, cwb = c & 1;
        int di = d0 + cd, hi = h0 + ch, wi = w0i + cwb;
        bool v = ((unsigned)di < 8u) && ((unsigned)hi < 48u) && ((unsigned)wi < 48u);
        float wg = (cd ? fd : 1.f - fd) * (ch ? fh : 1.f - fh) * (cwb ? fw : 1.f - fw);
        int dic = min(max(di, 0), 7), hic = min(max(hi, 0), 47), wic = min(max(wi, 0), 47);
        int idx = (dic * 48 + hic) * 48 + wic;
        scp[pl * 20 + c * 2] = (unsigned)idx;
        scp[pl * 20 + c * 2 + 1] = __float_as_uint(v ? wg : 0.f);
      }
    }
    __syncthreads();
    // ---- gather v2: unit id = u*256+t ; chg = id&7 (8-ch chunk), pos = id>>3
#pragma unroll
    for (int u = 0; u < 2; ++u) {
      int id = u * 256 + t;
      int chg = id & 7;
      int pl = id >> 3;
      const unsigned* sp = &scp[pl * 20];
      float a[8];
#pragma unroll
      for (int e = 0; e < 8; ++e) a[e] = 0.f;
#pragma unroll
      for (int cb2 = 0; cb2 < 2; ++cb2) {
        uint4 m0 = *reinterpret_cast<const uint4*>(sp + cb2 * 8);      // corners 4c, 4c+1
        uint4 m1 = *reinterpret_cast<const uint4*>(sp + cb2 * 8 + 4);  // corners 4c+2, 4c+3
        uint4 q0 = *reinterpret_cast<const uint4*>(xb8 + (((size_t)m0.x << 7) + (chg << 4)));
        uint4 q1 = *reinterpret_cast<const uint4*>(xb8 + (((size_t)m0.z << 7) + (chg << 4)));
        uint4 q2 = *reinterpret_cast<const uint4*>(xb8 + (((size_t)m1.x << 7) + (chg << 4)));
        uint4 q3 = *reinterpret_cast<const uint4*>(xb8 + (((size_t)m1.z << 7) + (chg << 4)));
        bfma8(a, q0, __uint_as_float(m0.y));
        bfma8(a, q1, __uint_as_float(m0.w));
        bfma8(a, q2, __uint_as_float(m1.y));
        bfma8(a, q3, __uint_as_float(m1.w));
      }
      unsigned pk[4];
#pragma unroll
      for (int e = 0; e < 4; ++e)
        pk[e] = (f2bf(a[2 * e + 1]) << 16) | f2bf(a[2 * e]);
      *reinterpret_cast<uint4*>(&vals[pl * 72 + chg * 8]) = uint4{pk[0], pk[1], pk[2], pk[3]};
    }
    __syncthreads();
    // ---- MFMA: C[co][pos] += W[co][cin] * V[cin][pos]; A from L2, B from LDS
    {
      const unsigned short* wk = wTb + (size_t)k * 4096;
#pragma unroll
      for (int s = 0; s < 2; ++s) {
        short8 bfr = *reinterpret_cast<const short8*>(
            &vals[(wv * 16 + (lane & 15)) * 72 + s * 32 + (lane >> 4) * 8]);
#pragma unroll
        for (int mt = 0; mt < 4; ++mt) {
          short8 afr = *reinterpret_cast<const short8*>(
              wk + mt * 1024 + s * 512 + (lane & 15) * 32 + (lane >> 4) * 8);
          acc[mt] = __builtin_amdgcn_mfma_f32_16x16x32_bf16(afr, bfr, acc[mt], 0, 0, 0);
        }
      }
    }
    __syncthreads();
  }

  // part[kc][b][tile][co][pos]; co = mt*16+(lane>>4)*4+reg, pos = wv*16+(lane&15)
  float* pp = part + ((size_t)(kc * 2 + b) * NTILE + tile) * 4096;
#pragma unroll
  for (int mt = 0; mt < 4; ++mt) {
#pragma unroll
    for (int reg = 0; reg < 4; ++reg) {
      int co = mt * 16 + (lane >> 4) * 4 + reg;
      pp[co * 64 + wv * 16 + (lane & 15)] = acc[mt][reg];
    }
  }
}

// out[b][co][p] = bias[co] + sum_kc part[kc][b][tile][co][pos]  (float4)
__global__ __launch_bounds__(256) void k_red(const float* __restrict__ part,
                                             const float* __restrict__ bias,
                                             float* __restrict__ out) {
  int i = blockIdx.x * 256 + threadIdx.x;  // 589,824 float4 units
  int p4 = i % (SP / 4);
  int co = (i / (SP / 4)) & 63;
  int b = i / ((SP / 4) * 64);
  int p = p4 * 4;
  int tile = p >> 6, pos = p & 63;
  size_t base = ((size_t)b * NTILE + tile) * 4096 + co * 64 + pos;
  float4 s = *reinterpret_cast<const float4*>(&part[base]);
#pragma unroll
  for (int kc = 1; kc < KC; ++kc) {
    float4 v = *reinterpret_cast<const float4*>(&part[base + (size_t)kc * (2 * NTILE * 4096)]);
    s.x += v.x; s.y += v.y; s.z += v.z; s.w += v.w;
  }
  float bb = bias[co];
  s.x += bb; s.y += bb; s.z += bb; s.w += bb;
  *reinterpret_cast<float4*>(&out[((size_t)(b * 64 + co)) * SP + p]) = s;
}

extern "C" void kernel_launch(void* const* d_in, const int* in_sizes, int n_in,
                              void* d_out, int out_size, void* d_ws, size_t ws_size,
                              hipStream_t stream) {
  const float* x = (const float*)d_in[0];
  const float* cw = (const float*)d_in[1];
  const float* cb = (const float*)d_in[2];
  const float* w = (const float*)d_in[3];
  const float* bias = (const float*)d_in[4];
  float* out = (float*)d_out;

  char* ws = (char*)d_ws;
  float* off = (float*)ws;                                   // 11,943,936 B
  unsigned short* xTh = (unsigned short*)(ws + 11943936);    //  4,718,592 B
  unsigned short* wTb = (unsigned short*)(ws + 16662528);    //    221,184 B
  unsigned short* wp = (unsigned short*)(ws + 16883712);     //    393,216 B
  float* part = (float*)(ws + 17276928);                     // KC * 9,437,184 B

  hipLaunchKernelGGL(k_xTh, dim3(9216), dim3(256), 0, stream, x, xTh);
  hipLaunchKernelGGL(k_wTb, dim3(432), dim3(256), 0, stream, w, wTb);
  hipLaunchKernelGGL(k_offw, dim3(768), dim3(256), 0, stream, cw, wp);
  hipLaunchKernelGGL(k_offm, dim3(576), dim3(256), 0, stream, x, wp, cb, off);
  hipLaunchKernelGGL(k_mainp, dim3(KC * 576), dim3(256), 0, stream, xTh, off, wTb, part);
  hipLaunchKernelGGL(k_red, dim3(2304), dim3(256), 0, stream, part, bias, out);
}

// Round 7
// 182.565 us; speedup vs baseline: 4.5525x; 1.0560x over previous
//
#include <hip/hip_runtime.h>

namespace {
constexpr int Bn = 2, Cin = 64, Cout = 64;
constexpr int Dd = 8, Hh = 48, Wd = 48;
constexpr int K = 27;
constexpr int SP = Dd * Hh * Wd;   // 18432
constexpr int PLANE = Hh * Wd;     // 2304
constexpr int NTILE = SP / 64;     // 288 position tiles per batch
constexpr int KC = 3;              // K-split factor (main GEMM)
constexpr int KPER = K / KC;       // 9
constexpr int CS = 4;              // cin-split factor (offset conv)
constexpr int CPER = Cin / CS;     // 16
}

typedef __attribute__((ext_vector_type(8))) short short8;
typedef __attribute__((ext_vector_type(4))) float f32x4;

__device__ __forceinline__ unsigned f2bf(float f) {  // RNE float->bf16 bits
  unsigned u = __float_as_uint(f);
  return (u + 0x7fffu + ((u >> 16) & 1u)) >> 16;
}

// x [B,C,D,H,W] -> xTh [B, spatial, C] bf16 (channels-last, halves gather bytes)
__global__ __launch_bounds__(256) void k_xTh(const float* __restrict__ x,
                                             unsigned short* __restrict__ xTh) {
  int i = blockIdx.x * 256 + threadIdx.x;   // B*SP*Cin = 2,359,296
  int c = i & 63;
  int rest = i >> 6;
  int p = rest % SP;
  int b = rest / SP;
  xTh[i] = (unsigned short)f2bf(x[(b * Cin + c) * SP + p]);
}

// main weights -> per-lane-contiguous MFMA A-frag layout, bf16:
// wTb[k][mt(4)][s(2)][row(16)][kg(4)][j(8)] ; co = mt*16+row, cin = s*32+kg*8+j
__global__ __launch_bounds__(256) void k_wTb(const float* __restrict__ w,
                                             unsigned short* __restrict__ wTb) {
  int i = blockIdx.x * 256 + threadIdx.x;   // 27*4096 = 110,592
  int j = i & 7, kg = (i >> 3) & 3, row = (i >> 5) & 15;
  int s = (i >> 9) & 1, mt = (i >> 10) & 3, k = i >> 12;
  int co = mt * 16 + row, cin = s * 32 + kg * 8 + j;
  wTb[i] = (unsigned short)f2bf(w[((size_t)co * Cin + cin) * K + k]);
}

// offset-conv weights -> wp[cin][ch(96, pad from 81)][tap(32, pad from 27)] bf16
__global__ __launch_bounds__(256) void k_offw(const float* __restrict__ cw,
                                              unsigned short* __restrict__ wp) {
  int i = blockIdx.x * 256 + threadIdx.x;   // 64*96*32 = 196,608
  int tap = i & 31;
  int ch = (i >> 5) % 96;
  int cin = i / 3072;
  float v = (ch < 81 && tap < 27) ? cw[((size_t)ch * 64 + cin) * 27 + tap] : 0.f;
  wp[i] = (unsigned short)f2bf(v);
}

// Offset conv as implicit-im2col MFMA GEMM, cin-split across CS block groups.
// Block = 64 positions x 16 cin; partial [81][pos] tiles to opart.
// Double-buffered B-tile: one barrier per cin iteration.
__global__ __launch_bounds__(256) void k_offm(const float* __restrict__ x,
                                              const unsigned short* __restrict__ wp,
                                              float* __restrict__ opart) {
  __shared__ unsigned short bt[2][64 * 40];  // [pos][tap], row stride 40 (80B)

  const int t = threadIdx.x;
  const int lane = t & 63;
  const int wv = t >> 6;
  const int bid = blockIdx.x;              // cs*576 + nb ; 2304 total
  const int cs = bid / 576;
  const int nb = bid - cs * 576;
  const int n0 = nb * 64;
  const int b = n0 / SP;
  const int sp0 = n0 - b * SP;
  const int cin0 = cs * CPER;

  int n = sp0 + lane;
  int d = n / PLANE;
  int r = n - d * PLANE;
  int h = r / 48;
  int w = r - h * 48;
  int ofs[8], msk[8];
#pragma unroll
  for (int j = 0; j < 8; ++j) {
    int tap = wv * 8 + j;
    int kd = tap / 9, kh2 = (tap - kd * 9) / 3, kw2 = tap - kd * 9 - kh2 * 3;
    int dd = d + kd - 1, hh = h + kh2 - 1, ww = w + kw2 - 1;
    bool v = (tap < 27) && ((unsigned)dd < 8u) && ((unsigned)hh < 48u) &&
             ((unsigned)ww < 48u);
    ofs[j] = v ? ((dd * 48 + hh) * 48 + ww) : 0;
    msk[j] = v ? -1 : 0;
  }
  const float* xb = x + (size_t)b * Cin * SP;
  const int arow = lane & 15, ak = (lane >> 4) * 8;

  f32x4 acc[6];
#pragma unroll
  for (int mt = 0; mt < 6; ++mt) acc[mt] = f32x4{0.f, 0.f, 0.f, 0.f};

  float pre[8];
#pragma unroll
  for (int j = 0; j < 8; ++j) pre[j] = xb[(size_t)cin0 * SP + ofs[j]];

  for (int i = 0; i < CPER; ++i) {
    const int cin = cin0 + i;
    unsigned pk[4];
#pragma unroll
    for (int q = 0; q < 4; ++q) {
      float lo = msk[2 * q] ? pre[2 * q] : 0.f;
      float hi = msk[2 * q + 1] ? pre[2 * q + 1] : 0.f;
      pk[q] = (f2bf(hi) << 16) | f2bf(lo);
    }
    *reinterpret_cast<uint4*>(&bt[i & 1][lane * 40 + wv * 8]) =
        uint4{pk[0], pk[1], pk[2], pk[3]};
    __syncthreads();   // writers done; prior-iteration readers already drained
    if (i + 1 < CPER) {
      const float* xn = xb + (size_t)(cin + 1) * SP;
#pragma unroll
      for (int j = 0; j < 8; ++j) pre[j] = xn[ofs[j]];
    }
    const unsigned short* wa = wp + (size_t)cin * 3072 + arow * 32 + ak;
    short8 af[6];
#pragma unroll
    for (int mt = 0; mt < 6; ++mt)
      af[mt] = *reinterpret_cast<const short8*>(wa + mt * 512);
    short8 bf = *reinterpret_cast<const short8*>(&bt[i & 1][(wv * 16 + arow) * 40 + ak]);
#pragma unroll
    for (int mt = 0; mt < 6; ++mt)
      acc[mt] = __builtin_amdgcn_mfma_f32_16x16x32_bf16(af[mt], bf, acc[mt], 0, 0, 0);
  }

  // opart[cs][b][ch][colp], ch<81
  int colp = sp0 + wv * 16 + (lane & 15);
  float* pp = opart + (size_t)(cs * 2 + b) * 81 * SP;
#pragma unroll
  for (int mt = 0; mt < 6; ++mt) {
#pragma unroll
    for (int reg = 0; reg < 4; ++reg) {
      int ch = mt * 16 + (lane >> 4) * 4 + reg;
      if (ch < 81)
        pp[(size_t)ch * SP + colp] = acc[mt][reg];
    }
  }
}

// off[b][ch][p] = cb[ch] + sum_cs opart[cs][b][ch][p]  (float4)
__global__ __launch_bounds__(256) void k_offred(const float* __restrict__ opart,
                                                const float* __restrict__ cb,
                                                float* __restrict__ off) {
  int i = blockIdx.x * 256 + threadIdx.x;  // 2*81*SP/4 = 746,496
  int p4 = i % (SP / 4);
  int ch = (i / (SP / 4)) % 81;
  int b = i / ((SP / 4) * 81);
  size_t base = ((size_t)b * 81 + ch) * SP + p4 * 4;
  float4 s = *reinterpret_cast<const float4*>(&opart[base]);
#pragma unroll
  for (int cs = 1; cs < CS; ++cs) {
    float4 v = *reinterpret_cast<const float4*>(&opart[base + (size_t)cs * 2 * 81 * SP]);
    s.x += v.x; s.y += v.y; s.z += v.z; s.w += v.w;
  }
  float bb = cb[ch];
  s.x += bb; s.y += bb; s.z += bb; s.w += bb;
  *reinterpret_cast<float4*>(&off[base]) = s;
}

__device__ __forceinline__ void bfma8(float* a, uint4 q, float wg) {
  unsigned u[4] = {q.x, q.y, q.z, q.w};
#pragma unroll
  for (int i = 0; i < 4; ++i) {
    float lo = __uint_as_float(u[i] << 16);
    float hi = __uint_as_float(u[i] & 0xffff0000u);
    a[2 * i] = fmaf(wg, lo, a[2 * i]);
    a[2 * i + 1] = fmaf(wg, hi, a[2 * i + 1]);
  }
}

// Fused gather + MFMA GEMM, K-split across blocks. Block tile: 64 pos x 64 co.
// XCD-aware tile swizzle; gather vectorized: 8 lanes share a position, each
// lane loads one 8-channel bf16 chunk (dwordx4) per corner.
__global__ __launch_bounds__(256, 6) void k_mainp(const unsigned short* __restrict__ xTh,
                                                  const float* __restrict__ off,
                                                  const unsigned short* __restrict__ wTb,
                                                  float* __restrict__ part) {
  __shared__ __align__(16) unsigned short vals[64 * 72]; // [pos][cin] bf16, stride 144 B
  __shared__ __align__(16) unsigned scp[64 * 20];        // [pos][8 x (idx,wgt)]

  const int t = threadIdx.x;
  const int bid = blockIdx.x;                    // kc*576 + j
  const int kc = bid / 576;
  const int j = bid - kc * 576;
  const int tl = (j & 7) * 72 + (j >> 3);        // XCD-contiguous tile blocks
  const int b = tl / NTILE;
  const int tile = tl - b * NTILE;
  const int p0 = tile * 64;

  const char* xb8 = (const char*)(xTh + (size_t)b * SP * 64);
  const float* offb = off + (size_t)b * 81 * SP;

  const int lane = t & 63;
  const int wv = t >> 6;

  f32x4 acc[4];
#pragma unroll
  for (int mt = 0; mt < 4; ++mt) acc[mt] = f32x4{0.f, 0.f, 0.f, 0.f};

  for (int kk = 0; kk < KPER; ++kk) {
    const int k = kc * KPER + kk;
    // ---- corner setup: pl = t&63, cg = t>>6 computes corners 2cg, 2cg+1
    {
      int pl = lane, cg = wv;
      int p = p0 + pl;
      int d = p / PLANE;
      int rp = p - d * PLANE;
      int h = rp / 48;
      int w = rp - h * 48;
      int kd = k / 9, kh = (k % 9) / 3, kw2 = k % 3;
      float pd = (float)(d + kd - 1) + offb[k * SP + p];
      float ph = (float)(h + kh - 1) + offb[(27 + k) * SP + p];
      float pw = (float)(w + kw2 - 1) + offb[(54 + k) * SP + p];
      float df = floorf(pd), hf = floorf(ph), wf = floorf(pw);
      float fd = pd - df, fh = ph - hf, fw = pw - wf;
      int d0 = (int)df, h0 = (int)hf, w0i = (int)wf;
#pragma unroll
      for (int cc = 0; cc < 2; ++cc) {
        int c = cg * 2 + cc;
        int cd = c >> 2, ch = (c >> 1) & 1, cwb = c & 1;
        int di = d0 + cd, hi = h0 + ch, wi = w0i + cwb;
        bool v = ((unsigned)di < 8u) && ((unsigned)hi < 48u) && ((unsigned)wi < 48u);
        float wg = (cd ? fd : 1.f - fd) * (ch ? fh : 1.f - fh) * (cwb ? fw : 1.f - fw);
        int dic = min(max(di, 0), 7), hic = min(max(hi, 0), 47), wic = min(max(wi, 0), 47);
        int idx = (dic * 48 + hic) * 48 + wic;
        scp[pl * 20 + c * 2] = (unsigned)idx;
        scp[pl * 20 + c * 2 + 1] = __float_as_uint(v ? wg : 0.f);
      }
    }
    __syncthreads();
    // ---- gather v2: unit id = u*256+t ; chg = id&7 (8-ch chunk), pos = id>>3
#pragma unroll
    for (int u = 0; u < 2; ++u) {
      int id = u * 256 + t;
      int chg = id & 7;
      int pl = id >> 3;
      const unsigned* sp = &scp[pl * 20];
      float a[8];
#pragma unroll
      for (int e = 0; e < 8; ++e) a[e] = 0.f;
#pragma unroll
      for (int cb2 = 0; cb2 < 2; ++cb2) {
        uint4 m0 = *reinterpret_cast<const uint4*>(sp + cb2 * 8);      // corners 4c, 4c+1
        uint4 m1 = *reinterpret_cast<const uint4*>(sp + cb2 * 8 + 4);  // corners 4c+2, 4c+3
        uint4 q0 = *reinterpret_cast<const uint4*>(xb8 + (((size_t)m0.x << 7) + (chg << 4)));
        uint4 q1 = *reinterpret_cast<const uint4*>(xb8 + (((size_t)m0.z << 7) + (chg << 4)));
        uint4 q2 = *reinterpret_cast<const uint4*>(xb8 + (((size_t)m1.x << 7) + (chg << 4)));
        uint4 q3 = *reinterpret_cast<const uint4*>(xb8 + (((size_t)m1.z << 7) + (chg << 4)));
        bfma8(a, q0, __uint_as_float(m0.y));
        bfma8(a, q1, __uint_as_float(m0.w));
        bfma8(a, q2, __uint_as_float(m1.y));
        bfma8(a, q3, __uint_as_float(m1.w));
      }
      unsigned pk[4];
#pragma unroll
      for (int e = 0; e < 4; ++e)
        pk[e] = (f2bf(a[2 * e + 1]) << 16) | f2bf(a[2 * e]);
      *reinterpret_cast<uint4*>(&vals[pl * 72 + chg * 8]) = uint4{pk[0], pk[1], pk[2], pk[3]};
    }
    __syncthreads();
    // ---- MFMA: C[co][pos] += W[co][cin] * V[cin][pos]; A from L2, B from LDS
    {
      const unsigned short* wk = wTb + (size_t)k * 4096;
#pragma unroll
      for (int s = 0; s < 2; ++s) {
        short8 bfr = *reinterpret_cast<const short8*>(
            &vals[(wv * 16 + (lane & 15)) * 72 + s * 32 + (lane >> 4) * 8]);
#pragma unroll
        for (int mt = 0; mt < 4; ++mt) {
          short8 afr = *reinterpret_cast<const short8*>(
              wk + mt * 1024 + s * 512 + (lane & 15) * 32 + (lane >> 4) * 8);
          acc[mt] = __builtin_amdgcn_mfma_f32_16x16x32_bf16(afr, bfr, acc[mt], 0, 0, 0);
        }
      }
    }
    __syncthreads();
  }

  // part[kc][b][tile][co][pos]; co = mt*16+(lane>>4)*4+reg, pos = wv*16+(lane&15)
  float* pp = part + ((size_t)(kc * 2 + b) * NTILE + tile) * 4096;
#pragma unroll
  for (int mt = 0; mt < 4; ++mt) {
#pragma unroll
    for (int reg = 0; reg < 4; ++reg) {
      int co = mt * 16 + (lane >> 4) * 4 + reg;
      pp[co * 64 + wv * 16 + (lane & 15)] = acc[mt][reg];
    }
  }
}

// out[b][co][p] = bias[co] + sum_kc part[kc][b][tile][co][pos]  (float4)
__global__ __launch_bounds__(256) void k_red(const float* __restrict__ part,
                                             const float* __restrict__ bias,
                                             float* __restrict__ out) {
  int i = blockIdx.x * 256 + threadIdx.x;  // 589,824 float4 units
  int p4 = i % (SP / 4);
  int co = (i / (SP / 4)) & 63;
  int b = i / ((SP / 4) * 64);
  int p = p4 * 4;
  int tile = p >> 6, pos = p & 63;
  size_t base = ((size_t)b * NTILE + tile) * 4096 + co * 64 + pos;
  float4 s = *reinterpret_cast<const float4*>(&part[base]);
#pragma unroll
  for (int kc = 1; kc < KC; ++kc) {
    float4 v = *reinterpret_cast<const float4*>(&part[base + (size_t)kc * (2 * NTILE * 4096)]);
    s.x += v.x; s.y += v.y; s.z += v.z; s.w += v.w;
  }
  float bb = bias[co];
  s.x += bb; s.y += bb; s.z += bb; s.w += bb;
  *reinterpret_cast<float4*>(&out[((size_t)(b * 64 + co)) * SP + p]) = s;
}

extern "C" void kernel_launch(void* const* d_in, const int* in_sizes, int n_in,
                              void* d_out, int out_size, void* d_ws, size_t ws_size,
                              hipStream_t stream) {
  const float* x = (const float*)d_in[0];
  const float* cw = (const float*)d_in[1];
  const float* cb = (const float*)d_in[2];
  const float* w = (const float*)d_in[3];
  const float* bias = (const float*)d_in[4];
  float* out = (float*)d_out;

  char* ws = (char*)d_ws;
  float* off = (float*)ws;                                   // 11,943,936 B
  unsigned short* xTh = (unsigned short*)(ws + 11943936);    //  4,718,592 B
  unsigned short* wTb = (unsigned short*)(ws + 16662528);    //    221,184 B
  unsigned short* wp = (unsigned short*)(ws + 16883712);     //    393,216 B
  float* part = (float*)(ws + 17276928);                     // KC*9,437,184 = 28,311,552 B
  float* opart = (float*)(ws + 45588480);                    // CS*11,943,936 = 47,775,744 B

  hipLaunchKernelGGL(k_xTh, dim3(9216), dim3(256), 0, stream, x, xTh);
  hipLaunchKernelGGL(k_wTb, dim3(432), dim3(256), 0, stream, w, wTb);
  hipLaunchKernelGGL(k_offw, dim3(768), dim3(256), 0, stream, cw, wp);
  hipLaunchKernelGGL(k_offm, dim3(CS * 576), dim3(256), 0, stream, x, wp, opart);
  hipLaunchKernelGGL(k_offred, dim3(2916), dim3(256), 0, stream, opart, cb, off);
  hipLaunchKernelGGL(k_mainp, dim3(KC * 576), dim3(256), 0, stream, xTh, off, wTb, part);
  hipLaunchKernelGGL(k_red, dim3(2304), dim3(256), 0, stream, part, bias, out);
}

// Round 8
// 172.147 us; speedup vs baseline: 4.8280x; 1.0605x over previous
//
#include <hip/hip_runtime.h>
#include <hip/hip_fp16.h>

namespace {
constexpr int Bn = 2, Cin = 64, Cout = 64;
constexpr int Dd = 8, Hh = 48, Wd = 48;
constexpr int K = 27;
constexpr int SP = Dd * Hh * Wd;   // 18432
constexpr int PLANE = Hh * Wd;     // 2304
constexpr int NTILE = SP / 64;     // 288 position tiles per batch
constexpr int KC = 3;              // K-split factor (main GEMM)
constexpr int KPER = K / KC;       // 9
constexpr int CS = 4;              // cin-split factor (offset conv)
constexpr int CPER = Cin / CS;     // 16
}

typedef __attribute__((ext_vector_type(8))) _Float16 half8;
typedef __attribute__((ext_vector_type(4))) float f32x4;

__device__ __forceinline__ unsigned short f2h(float f) {  // RNE float->f16 bits
  return __half_as_ushort(__float2half(f));
}
__device__ __forceinline__ __half2 u2h2(unsigned u) {
  return __builtin_bit_cast(__half2, u);
}
__device__ __forceinline__ unsigned h22u(__half2 h) {
  return __builtin_bit_cast(unsigned, h);
}

// x [B,C,D,H,W] -> xTh [B, spatial, C] f16 (channels-last, halves gather bytes)
__global__ __launch_bounds__(256) void k_xTh(const float* __restrict__ x,
                                             unsigned short* __restrict__ xTh) {
  int i = blockIdx.x * 256 + threadIdx.x;   // B*SP*Cin = 2,359,296
  int c = i & 63;
  int rest = i >> 6;
  int p = rest % SP;
  int b = rest / SP;
  xTh[i] = f2h(x[(b * Cin + c) * SP + p]);
}

// main weights -> per-lane-contiguous MFMA A-frag layout, f16:
// wTb[k][mt(4)][s(2)][row(16)][kg(4)][j(8)] ; co = mt*16+row, cin = s*32+kg*8+j
__global__ __launch_bounds__(256) void k_wTb(const float* __restrict__ w,
                                             unsigned short* __restrict__ wTb) {
  int i = blockIdx.x * 256 + threadIdx.x;   // 27*4096 = 110,592
  int j = i & 7, kg = (i >> 3) & 3, row = (i >> 5) & 15;
  int s = (i >> 9) & 1, mt = (i >> 10) & 3, k = i >> 12;
  int co = mt * 16 + row, cin = s * 32 + kg * 8 + j;
  wTb[i] = f2h(w[((size_t)co * Cin + cin) * K + k]);
}

// offset-conv weights -> wp[cin][ch(96, pad from 81)][tap(32, pad from 27)] f16
__global__ __launch_bounds__(256) void k_offw(const float* __restrict__ cw,
                                              unsigned short* __restrict__ wp) {
  int i = blockIdx.x * 256 + threadIdx.x;   // 64*96*32 = 196,608
  int tap = i & 31;
  int ch = (i >> 5) % 96;
  int cin = i / 3072;
  float v = (ch < 81 && tap < 27) ? cw[((size_t)ch * 64 + cin) * 27 + tap] : 0.f;
  wp[i] = f2h(v);
}

// Offset conv as implicit-im2col MFMA GEMM, cin-split across CS block groups.
__global__ __launch_bounds__(256) void k_offm(const float* __restrict__ x,
                                              const unsigned short* __restrict__ wp,
                                              float* __restrict__ opart) {
  __shared__ unsigned short bt[2][64 * 40];  // [pos][tap], row stride 40 (80B)

  const int t = threadIdx.x;
  const int lane = t & 63;
  const int wv = t >> 6;
  const int bid = blockIdx.x;              // cs*576 + nb ; 2304 total
  const int cs = bid / 576;
  const int nb = bid - cs * 576;
  const int n0 = nb * 64;
  const int b = n0 / SP;
  const int sp0 = n0 - b * SP;
  const int cin0 = cs * CPER;

  int n = sp0 + lane;
  int d = n / PLANE;
  int r = n - d * PLANE;
  int h = r / 48;
  int w = r - h * 48;
  int ofs[8], msk[8];
#pragma unroll
  for (int j = 0; j < 8; ++j) {
    int tap = wv * 8 + j;
    int kd = tap / 9, kh2 = (tap - kd * 9) / 3, kw2 = tap - kd * 9 - kh2 * 3;
    int dd = d + kd - 1, hh = h + kh2 - 1, ww = w + kw2 - 1;
    bool v = (tap < 27) && ((unsigned)dd < 8u) && ((unsigned)hh < 48u) &&
             ((unsigned)ww < 48u);
    ofs[j] = v ? ((dd * 48 + hh) * 48 + ww) : 0;
    msk[j] = v ? -1 : 0;
  }
  const float* xb = x + (size_t)b * Cin * SP;
  const int arow = lane & 15, ak = (lane >> 4) * 8;

  f32x4 acc[6];
#pragma unroll
  for (int mt = 0; mt < 6; ++mt) acc[mt] = f32x4{0.f, 0.f, 0.f, 0.f};

  float pre[8];
#pragma unroll
  for (int j = 0; j < 8; ++j) pre[j] = xb[(size_t)cin0 * SP + ofs[j]];

  for (int i = 0; i < CPER; ++i) {
    const int cin = cin0 + i;
    unsigned pk[4];
#pragma unroll
    for (int q = 0; q < 4; ++q) {
      float lo = msk[2 * q] ? pre[2 * q] : 0.f;
      float hi = msk[2 * q + 1] ? pre[2 * q + 1] : 0.f;
      pk[q] = (unsigned)f2h(lo) | ((unsigned)f2h(hi) << 16);
    }
    *reinterpret_cast<uint4*>(&bt[i & 1][lane * 40 + wv * 8]) =
        uint4{pk[0], pk[1], pk[2], pk[3]};
    __syncthreads();   // writers done; prior-iteration readers already drained
    if (i + 1 < CPER) {
      const float* xn = xb + (size_t)(cin + 1) * SP;
#pragma unroll
      for (int j = 0; j < 8; ++j) pre[j] = xn[ofs[j]];
    }
    const unsigned short* wa = wp + (size_t)cin * 3072 + arow * 32 + ak;
    half8 af[6];
#pragma unroll
    for (int mt = 0; mt < 6; ++mt)
      af[mt] = *reinterpret_cast<const half8*>(wa + mt * 512);
    half8 bf = *reinterpret_cast<const half8*>(&bt[i & 1][(wv * 16 + arow) * 40 + ak]);
#pragma unroll
    for (int mt = 0; mt < 6; ++mt)
      acc[mt] = __builtin_amdgcn_mfma_f32_16x16x32_f16(af[mt], bf, acc[mt], 0, 0, 0);
  }

  // opart[cs][b][ch][colp], ch<81
  int colp = sp0 + wv * 16 + (lane & 15);
  float* pp = opart + (size_t)(cs * 2 + b) * 81 * SP;
#pragma unroll
  for (int mt = 0; mt < 6; ++mt) {
#pragma unroll
    for (int reg = 0; reg < 4; ++reg) {
      int ch = mt * 16 + (lane >> 4) * 4 + reg;
      if (ch < 81)
        pp[(size_t)ch * SP + colp] = acc[mt][reg];
    }
  }
}

// off[b][ch][p] = cb[ch] + sum_cs opart[cs][b][ch][p]  (float4)
__global__ __launch_bounds__(256) void k_offred(const float* __restrict__ opart,
                                                const float* __restrict__ cb,
                                                float* __restrict__ off) {
  int i = blockIdx.x * 256 + threadIdx.x;  // 2*81*SP/4 = 746,496
  int p4 = i % (SP / 4);
  int ch = (i / (SP / 4)) % 81;
  int b = i / ((SP / 4) * 81);
  size_t base = ((size_t)b * 81 + ch) * SP + p4 * 4;
  float4 s = *reinterpret_cast<const float4*>(&opart[base]);
#pragma unroll
  for (int cs = 1; cs < CS; ++cs) {
    float4 v = *reinterpret_cast<const float4*>(&opart[base + (size_t)cs * 2 * 81 * SP]);
    s.x += v.x; s.y += v.y; s.z += v.z; s.w += v.w;
  }
  float bb = cb[ch];
  s.x += bb; s.y += bb; s.z += bb; s.w += bb;
  *reinterpret_cast<float4*>(&off[base]) = s;
}

// Fused gather + MFMA GEMM, K-split across blocks. Block tile: 64 pos x 64 co.
// XCD-aware tile swizzle; gather: 8 lanes share a position, each lane owns an
// 8-channel f16 chunk; blend via v_pk_fma_f16 (result is already-packed f16).
__global__ __launch_bounds__(256, 6) void k_mainp(const unsigned short* __restrict__ xTh,
                                                  const float* __restrict__ off,
                                                  const unsigned short* __restrict__ wTb,
                                                  float* __restrict__ part) {
  __shared__ __align__(16) unsigned short vals[64 * 72]; // [pos][cin] f16, stride 144 B
  __shared__ __align__(16) unsigned scp[64 * 20];        // [pos][8 x (idx, wgt-half2)]

  const int t = threadIdx.x;
  const int bid = blockIdx.x;                    // kc*576 + j
  const int kc = bid / 576;
  const int j = bid - kc * 576;
  const int tl = (j & 7) * 72 + (j >> 3);        // XCD-contiguous tile blocks
  const int b = tl / NTILE;
  const int tile = tl - b * NTILE;
  const int p0 = tile * 64;

  const char* xb8 = (const char*)(xTh + (size_t)b * SP * 64);
  const float* offb = off + (size_t)b * 81 * SP;

  const int lane = t & 63;
  const int wv = t >> 6;

  f32x4 acc[4];
#pragma unroll
  for (int mt = 0; mt < 4; ++mt) acc[mt] = f32x4{0.f, 0.f, 0.f, 0.f};

  for (int kk = 0; kk < KPER; ++kk) {
    const int k = kc * KPER + kk;
    // ---- corner setup: pl = t&63, cg = t>>6 computes corners 2cg, 2cg+1
    {
      int pl = lane, cg = wv;
      int p = p0 + pl;
      int d = p / PLANE;
      int rp = p - d * PLANE;
      int h = rp / 48;
      int w = rp - h * 48;
      int kd = k / 9, kh = (k % 9) / 3, kw2 = k % 3;
      float pd = (float)(d + kd - 1) + offb[k * SP + p];
      float ph = (float)(h + kh - 1) + offb[(27 + k) * SP + p];
      float pw = (float)(w + kw2 - 1) + offb[(54 + k) * SP + p];
      float df = floorf(pd), hf = floorf(ph), wf = floorf(pw);
      float fd = pd - df, fh = ph - hf, fw = pw - wf;
      int d0 = (int)df, h0 = (int)hf, w0i = (int)wf;
#pragma unroll
      for (int cc = 0; cc < 2; ++cc) {
        int c = cg * 2 + cc;
        int cd = c >> 2, ch = (c >> 1) & 1, cwb = c & 1;
        int di = d0 + cd, hi = h0 + ch, wi = w0i + cwb;
        bool v = ((unsigned)di < 8u) && ((unsigned)hi < 48u) && ((unsigned)wi < 48u);
        float wg = (cd ? fd : 1.f - fd) * (ch ? fh : 1.f - fh) * (cwb ? fw : 1.f - fw);
        int dic = min(max(di, 0), 7), hic = min(max(hi, 0), 47), wic = min(max(wi, 0), 47);
        int idx = (dic * 48 + hic) * 48 + wic;
        unsigned hs = (unsigned)f2h(v ? wg : 0.f);
        scp[pl * 20 + c * 2] = (unsigned)idx;
        scp[pl * 20 + c * 2 + 1] = hs | (hs << 16);   // pre-packed half2 weight
      }
    }
    __syncthreads();
    // ---- gather: unit id = u*256+t ; chg = id&7 (8-ch chunk), pos = id>>3
#pragma unroll
    for (int u = 0; u < 2; ++u) {
      int id = u * 256 + t;
      int chg = id & 7;
      int pl = id >> 3;
      const unsigned* sp = &scp[pl * 20];
      __half2 a2[4];
#pragma unroll
      for (int e = 0; e < 4; ++e) a2[e] = u2h2(0u);
#pragma unroll
      for (int cb2 = 0; cb2 < 2; ++cb2) {
        uint4 m0 = *reinterpret_cast<const uint4*>(sp + cb2 * 8);      // corners 4c, 4c+1
        uint4 m1 = *reinterpret_cast<const uint4*>(sp + cb2 * 8 + 4);  // corners 4c+2, 4c+3
        uint4 q0 = *reinterpret_cast<const uint4*>(xb8 + (((size_t)m0.x << 7) + (chg << 4)));
        uint4 q1 = *reinterpret_cast<const uint4*>(xb8 + (((size_t)m0.z << 7) + (chg << 4)));
        uint4 q2 = *reinterpret_cast<const uint4*>(xb8 + (((size_t)m1.x << 7) + (chg << 4)));
        uint4 q3 = *reinterpret_cast<const uint4*>(xb8 + (((size_t)m1.z << 7) + (chg << 4)));
        __half2 w0 = u2h2(m0.y), w1 = u2h2(m0.w), w2 = u2h2(m1.y), w3 = u2h2(m1.w);
        a2[0] = __hfma2(u2h2(q0.x), w0, a2[0]);
        a2[1] = __hfma2(u2h2(q0.y), w0, a2[1]);
        a2[2] = __hfma2(u2h2(q0.z), w0, a2[2]);
        a2[3] = __hfma2(u2h2(q0.w), w0, a2[3]);
        a2[0] = __hfma2(u2h2(q1.x), w1, a2[0]);
        a2[1] = __hfma2(u2h2(q1.y), w1, a2[1]);
        a2[2] = __hfma2(u2h2(q1.z), w1, a2[2]);
        a2[3] = __hfma2(u2h2(q1.w), w1, a2[3]);
        a2[0] = __hfma2(u2h2(q2.x), w2, a2[0]);
        a2[1] = __hfma2(u2h2(q2.y), w2, a2[1]);
        a2[2] = __hfma2(u2h2(q2.z), w2, a2[2]);
        a2[3] = __hfma2(u2h2(q2.w), w2, a2[3]);
        a2[0] = __hfma2(u2h2(q3.x), w3, a2[0]);
        a2[1] = __hfma2(u2h2(q3.y), w3, a2[1]);
        a2[2] = __hfma2(u2h2(q3.z), w3, a2[2]);
        a2[3] = __hfma2(u2h2(q3.w), w3, a2[3]);
      }
      *reinterpret_cast<uint4*>(&vals[pl * 72 + chg * 8]) =
          uint4{h22u(a2[0]), h22u(a2[1]), h22u(a2[2]), h22u(a2[3])};
    }
    __syncthreads();
    // ---- MFMA: C[co][pos] += W[co][cin] * V[cin][pos]; A from L2, B from LDS
    {
      const unsigned short* wk = wTb + (size_t)k * 4096;
#pragma unroll
      for (int s = 0; s < 2; ++s) {
        half8 bfr = *reinterpret_cast<const half8*>(
            &vals[(wv * 16 + (lane & 15)) * 72 + s * 32 + (lane >> 4) * 8]);
#pragma unroll
        for (int mt = 0; mt < 4; ++mt) {
          half8 afr = *reinterpret_cast<const half8*>(
              wk + mt * 1024 + s * 512 + (lane & 15) * 32 + (lane >> 4) * 8);
          acc[mt] = __builtin_amdgcn_mfma_f32_16x16x32_f16(afr, bfr, acc[mt], 0, 0, 0);
        }
      }
    }
    __syncthreads();
  }

  // part[kc][b][tile][co][pos]; co = mt*16+(lane>>4)*4+reg, pos = wv*16+(lane&15)
  float* pp = part + ((size_t)(kc * 2 + b) * NTILE + tile) * 4096;
#pragma unroll
  for (int mt = 0; mt < 4; ++mt) {
#pragma unroll
    for (int reg = 0; reg < 4; ++reg) {
      int co = mt * 16 + (lane >> 4) * 4 + reg;
      pp[co * 64 + wv * 16 + (lane & 15)] = acc[mt][reg];
    }
  }
}

// out[b][co][p] = bias[co] + sum_kc part[kc][b][tile][co][pos]  (float4)
__global__ __launch_bounds__(256) void k_red(const float* __restrict__ part,
                                             const float* __restrict__ bias,
                                             float* __restrict__ out) {
  int i = blockIdx.x * 256 + threadIdx.x;  // 589,824 float4 units
  int p4 = i % (SP / 4);
  int co = (i / (SP / 4)) & 63;
  int b = i / ((SP / 4) * 64);
  int p = p4 * 4;
  int tile = p >> 6, pos = p & 63;
  size_t base = ((size_t)b * NTILE + tile) * 4096 + co * 64 + pos;
  float4 s = *reinterpret_cast<const float4*>(&part[base]);
#pragma unroll
  for (int kc = 1; kc < KC; ++kc) {
    float4 v = *reinterpret_cast<const float4*>(&part[base + (size_t)kc * (2 * NTILE * 4096)]);
    s.x += v.x; s.y += v.y; s.z += v.z; s.w += v.w;
  }
  float bb = bias[co];
  s.x += bb; s.y += bb; s.z += bb; s.w += bb;
  *reinterpret_cast<float4*>(&out[((size_t)(b * 64 + co)) * SP + p]) = s;
}

extern "C" void kernel_launch(void* const* d_in, const int* in_sizes, int n_in,
                              void* d_out, int out_size, void* d_ws, size_t ws_size,
                              hipStream_t stream) {
  const float* x = (const float*)d_in[0];
  const float* cw = (const float*)d_in[1];
  const float* cb = (const float*)d_in[2];
  const float* w = (const float*)d_in[3];
  const float* bias = (const float*)d_in[4];
  float* out = (float*)d_out;

  char* ws = (char*)d_ws;
  float* off = (float*)ws;                                   // 11,943,936 B
  unsigned short* xTh = (unsigned short*)(ws + 11943936);    //  4,718,592 B
  unsigned short* wTb = (unsigned short*)(ws + 16662528);    //    221,184 B
  unsigned short* wp = (unsigned short*)(ws + 16883712);     //    393,216 B
  float* part = (float*)(ws + 17276928);                     // KC*9,437,184 = 28,311,552 B
  float* opart = (float*)(ws + 45588480);                    // CS*11,943,936 = 47,775,744 B

  hipLaunchKernelGGL(k_xTh, dim3(9216), dim3(256), 0, stream, x, xTh);
  hipLaunchKernelGGL(k_wTb, dim3(432), dim3(256), 0, stream, w, wTb);
  hipLaunchKernelGGL(k_offw, dim3(768), dim3(256), 0, stream, cw, wp);
  hipLaunchKernelGGL(k_offm, dim3(CS * 576), dim3(256), 0, stream, x, wp, opart);
  hipLaunchKernelGGL(k_offred, dim3(2916), dim3(256), 0, stream, opart, cb, off);
  hipLaunchKernelGGL(k_mainp, dim3(KC * 576), dim3(256), 0, stream, xTh, off, wTb, part);
  hipLaunchKernelGGL(k_red, dim3(2304), dim3(256), 0, stream, part, bias, out);
}

// Round 9
// 162.064 us; speedup vs baseline: 5.1284x; 1.0622x over previous
//
#include <hip/hip_runtime.h>
#include <hip/hip_fp16.h>

namespace {
constexpr int Bn = 2, Cin = 64, Cout = 64;
constexpr int Dd = 8, Hh = 48, Wd = 48;
constexpr int K = 27;
constexpr int SP = Dd * Hh * Wd;   // 18432
constexpr int PLANE = Hh * Wd;     // 2304
constexpr int NTILE = SP / 64;     // 288 position tiles per batch
constexpr int KC = 3;              // K-split factor (main GEMM)
constexpr int KPER = K / KC;       // 9
constexpr int CS = 2;              // cin-split factor (offset conv)
}

typedef __attribute__((ext_vector_type(8))) _Float16 half8;
typedef __attribute__((ext_vector_type(4))) float f32x4;

__device__ __forceinline__ unsigned short f2h(float f) {  // RNE float->f16 bits
  return __half_as_ushort(__float2half(f));
}
__device__ __forceinline__ __half2 u2h2(unsigned u) {
  return __builtin_bit_cast(__half2, u);
}
__device__ __forceinline__ unsigned h22u(__half2 h) {
  return __builtin_bit_cast(unsigned, h);
}

// x [B,C,D,H,W] -> xTh [B, spatial, C] f16 (channels-last)
__global__ __launch_bounds__(256) void k_xTh(const float* __restrict__ x,
                                             unsigned short* __restrict__ xTh) {
  int i = blockIdx.x * 256 + threadIdx.x;   // B*SP*Cin = 2,359,296
  int c = i & 63;
  int rest = i >> 6;
  int p = rest % SP;
  int b = rest / SP;
  xTh[i] = f2h(x[(b * Cin + c) * SP + p]);
}

// main weights -> per-lane-contiguous MFMA A-frag layout, f16:
// wTb[k][mt(4)][s(2)][row(16)][kg(4)][j(8)] ; co = mt*16+row, cin = s*32+kg*8+j
__global__ __launch_bounds__(256) void k_wTb(const float* __restrict__ w,
                                             unsigned short* __restrict__ wTb) {
  int i = blockIdx.x * 256 + threadIdx.x;   // 27*4096 = 110,592
  int j = i & 7, kg = (i >> 3) & 3, row = (i >> 5) & 15;
  int s = (i >> 9) & 1, mt = (i >> 10) & 3, k = i >> 12;
  int co = mt * 16 + row, cin = s * 32 + kg * 8 + j;
  wTb[i] = f2h(w[((size_t)co * Cin + cin) * K + k]);
}

// offset-conv weights -> A-frag layout keyed by (tap, cin-half):
// wq[tap][cs(2)][mt(6)][row(16)][kg(4)][j(8)] ; ch = mt*16+row (pad >=81 -> 0),
// cin = cs*32+kg*8+j
__global__ __launch_bounds__(256) void k_offwq(const float* __restrict__ cw,
                                               unsigned short* __restrict__ wq) {
  int i = blockIdx.x * 256 + threadIdx.x;   // 27*2*6*512 = 165,888
  int j = i & 7, kg = (i >> 3) & 3, row = (i >> 5) & 15;
  int rest = i >> 9;          // 0..323
  int mt = rest % 6;
  int rest2 = rest / 6;       // 0..53
  int cs = rest2 & 1;
  int tap = rest2 >> 1;
  int ch = mt * 16 + row, cin = cs * 32 + kg * 8 + j;
  float v = (ch < 81) ? cw[((size_t)ch * 64 + cin) * 27 + tap] : 0.f;
  wq[i] = f2h(v);
}

// Offset conv, barrier-free MFMA: off[ch][pos] = sum_tap A_tap[ch][cin] * xTh[pos+dtap][cin].
// Block = 64 positions x 32 cin (cs half); per tap: 1 masked B-load (16B/lane,
// direct from xTh/L2) + 6 A-frag loads (wq, L2-resident) + 6 MFMAs. No LDS.
__global__ __launch_bounds__(256) void k_offm3(const unsigned short* __restrict__ xTh,
                                               const unsigned short* __restrict__ wq,
                                               float* __restrict__ opart) {
  const int t = threadIdx.x;
  const int lane = t & 63;
  const int wv = t >> 6;
  const int bid = blockIdx.x;              // cs*576 + nb ; 1152 total
  const int cs = bid / 576;
  const int nb = bid - cs * 576;
  const int n0 = nb * 64;
  const int b = n0 / SP;
  const int sp0 = n0 - b * SP;

  const int q = sp0 + wv * 16 + (lane & 15);   // this lane's output position
  const int d = q / PLANE;
  const int rp = q - d * PLANE;
  const int h = rp / 48;
  const int w = rp - h * 48;

  const unsigned short* xb =
      xTh + ((size_t)b * SP + q) * 64 + cs * 32 + (lane >> 4) * 8;
  const unsigned short* wbase =
      wq + cs * 3072 + (lane & 15) * 32 + (lane >> 4) * 8;

  f32x4 acc[6];
#pragma unroll
  for (int mt = 0; mt < 6; ++mt) acc[mt] = f32x4{0.f, 0.f, 0.f, 0.f};

#pragma unroll
  for (int tap = 0; tap < 27; ++tap) {
    const int kd = tap / 9, kh = (tap % 9) / 3, kw = tap % 3;
    const int dd = d + kd - 1, hh = h + kh - 1, ww = w + kw - 1;
    const bool valid = ((unsigned)dd < 8u) & ((unsigned)hh < 48u) & ((unsigned)ww < 48u);
    const int delta = ((kd - 1) * PLANE + (kh - 1) * 48 + (kw - 1)) * 64;
    half8 bf = {};
    if (valid) bf = *reinterpret_cast<const half8*>(xb + delta);
    const unsigned short* wt = wbase + tap * 6144;
#pragma unroll
    for (int mt = 0; mt < 6; ++mt) {
      half8 af = *reinterpret_cast<const half8*>(wt + mt * 512);
      acc[mt] = __builtin_amdgcn_mfma_f32_16x16x32_f16(af, bf, acc[mt], 0, 0, 0);
    }
  }

  // opart[cs][b][ch][colp], ch<81
  const int colp = sp0 + wv * 16 + (lane & 15);
  float* pp = opart + (size_t)(cs * 2 + b) * 81 * SP;
#pragma unroll
  for (int mt = 0; mt < 6; ++mt) {
#pragma unroll
    for (int reg = 0; reg < 4; ++reg) {
      int ch = mt * 16 + (lane >> 4) * 4 + reg;
      if (ch < 81)
        pp[(size_t)ch * SP + colp] = acc[mt][reg];
    }
  }
}

// off[b][ch][p] = cb[ch] + sum_cs opart[cs][b][ch][p]  (float4)
__global__ __launch_bounds__(256) void k_offred(const float* __restrict__ opart,
                                                const float* __restrict__ cb,
                                                float* __restrict__ off) {
  int i = blockIdx.x * 256 + threadIdx.x;  // 2*81*SP/4 = 746,496
  int p4 = i % (SP / 4);
  int ch = (i / (SP / 4)) % 81;
  int b = i / ((SP / 4) * 81);
  size_t base = ((size_t)b * 81 + ch) * SP + p4 * 4;
  float4 s = *reinterpret_cast<const float4*>(&opart[base]);
#pragma unroll
  for (int cs = 1; cs < CS; ++cs) {
    float4 v = *reinterpret_cast<const float4*>(&opart[base + (size_t)cs * 2 * 81 * SP]);
    s.x += v.x; s.y += v.y; s.z += v.z; s.w += v.w;
  }
  float bb = cb[ch];
  s.x += bb; s.y += bb; s.z += bb; s.w += bb;
  *reinterpret_cast<float4*>(&off[base]) = s;
}

// Fused gather + MFMA GEMM, K-split across blocks. Block tile: 64 pos x 64 co.
// XCD-aware tile swizzle; gather: 8 lanes share a position, each lane owns an
// 8-channel f16 chunk; blend via v_pk_fma_f16 (result is already-packed f16).
__global__ __launch_bounds__(256, 6) void k_mainp(const unsigned short* __restrict__ xTh,
                                                  const float* __restrict__ off,
                                                  const unsigned short* __restrict__ wTb,
                                                  float* __restrict__ part) {
  __shared__ __align__(16) unsigned short vals[64 * 72]; // [pos][cin] f16, stride 144 B
  __shared__ __align__(16) unsigned scp[64 * 20];        // [pos][8 x (idx, wgt-half2)]

  const int t = threadIdx.x;
  const int bid = blockIdx.x;                    // kc*576 + j
  const int kc = bid / 576;
  const int j = bid - kc * 576;
  const int tl = (j & 7) * 72 + (j >> 3);        // XCD-contiguous tile blocks
  const int b = tl / NTILE;
  const int tile = tl - b * NTILE;
  const int p0 = tile * 64;

  const char* xb8 = (const char*)(xTh + (size_t)b * SP * 64);
  const float* offb = off + (size_t)b * 81 * SP;

  const int lane = t & 63;
  const int wv = t >> 6;

  f32x4 acc[4];
#pragma unroll
  for (int mt = 0; mt < 4; ++mt) acc[mt] = f32x4{0.f, 0.f, 0.f, 0.f};

  for (int kk = 0; kk < KPER; ++kk) {
    const int k = kc * KPER + kk;
    // ---- corner setup: pl = t&63, cg = t>>6 computes corners 2cg, 2cg+1
    {
      int pl = lane, cg = wv;
      int p = p0 + pl;
      int d = p / PLANE;
      int rp = p - d * PLANE;
      int h = rp / 48;
      int w = rp - h * 48;
      int kd = k / 9, kh = (k % 9) / 3, kw2 = k % 3;
      float pd = (float)(d + kd - 1) + offb[k * SP + p];
      float ph = (float)(h + kh - 1) + offb[(27 + k) * SP + p];
      float pw = (float)(w + kw2 - 1) + offb[(54 + k) * SP + p];
      float df = floorf(pd), hf = floorf(ph), wf = floorf(pw);
      float fd = pd - df, fh = ph - hf, fw = pw - wf;
      int d0 = (int)df, h0 = (int)hf, w0i = (int)wf;
#pragma unroll
      for (int cc = 0; cc < 2; ++cc) {
        int c = cg * 2 + cc;
        int cd = c >> 2, ch = (c >> 1) & 1, cwb = c & 1;
        int di = d0 + cd, hi = h0 + ch, wi = w0i + cwb;
        bool v = ((unsigned)di < 8u) && ((unsigned)hi < 48u) && ((unsigned)wi < 48u);
        float wg = (cd ? fd : 1.f - fd) * (ch ? fh : 1.f - fh) * (cwb ? fw : 1.f - fw);
        int dic = min(max(di, 0), 7), hic = min(max(hi, 0), 47), wic = min(max(wi, 0), 47);
        int idx = (dic * 48 + hic) * 48 + wic;
        unsigned hs = (unsigned)f2h(v ? wg : 0.f);
        scp[pl * 20 + c * 2] = (unsigned)idx;
        scp[pl * 20 + c * 2 + 1] = hs | (hs << 16);   // pre-packed half2 weight
      }
    }
    __syncthreads();
    // ---- gather: unit id = u*256+t ; chg = id&7 (8-ch chunk), pos = id>>3
#pragma unroll
    for (int u = 0; u < 2; ++u) {
      int id = u * 256 + t;
      int chg = id & 7;
      int pl = id >> 3;
      const unsigned* sp = &scp[pl * 20];
      __half2 a2[4];
#pragma unroll
      for (int e = 0; e < 4; ++e) a2[e] = u2h2(0u);
#pragma unroll
      for (int cb2 = 0; cb2 < 2; ++cb2) {
        uint4 m0 = *reinterpret_cast<const uint4*>(sp + cb2 * 8);      // corners 4c, 4c+1
        uint4 m1 = *reinterpret_cast<const uint4*>(sp + cb2 * 8 + 4);  // corners 4c+2, 4c+3
        uint4 q0 = *reinterpret_cast<const uint4*>(xb8 + (((size_t)m0.x << 7) + (chg << 4)));
        uint4 q1 = *reinterpret_cast<const uint4*>(xb8 + (((size_t)m0.z << 7) + (chg << 4)));
        uint4 q2 = *reinterpret_cast<const uint4*>(xb8 + (((size_t)m1.x << 7) + (chg << 4)));
        uint4 q3 = *reinterpret_cast<const uint4*>(xb8 + (((size_t)m1.z << 7) + (chg << 4)));
        __half2 w0 = u2h2(m0.y), w1 = u2h2(m0.w), w2 = u2h2(m1.y), w3 = u2h2(m1.w);
        a2[0] = __hfma2(u2h2(q0.x), w0, a2[0]);
        a2[1] = __hfma2(u2h2(q0.y), w0, a2[1]);
        a2[2] = __hfma2(u2h2(q0.z), w0, a2[2]);
        a2[3] = __hfma2(u2h2(q0.w), w0, a2[3]);
        a2[0] = __hfma2(u2h2(q1.x), w1, a2[0]);
        a2[1] = __hfma2(u2h2(q1.y), w1, a2[1]);
        a2[2] = __hfma2(u2h2(q1.z), w1, a2[2]);
        a2[3] = __hfma2(u2h2(q1.w), w1, a2[3]);
        a2[0] = __hfma2(u2h2(q2.x), w2, a2[0]);
        a2[1] = __hfma2(u2h2(q2.y), w2, a2[1]);
        a2[2] = __hfma2(u2h2(q2.z), w2, a2[2]);
        a2[3] = __hfma2(u2h2(q2.w), w2, a2[3]);
        a2[0] = __hfma2(u2h2(q3.x), w3, a2[0]);
        a2[1] = __hfma2(u2h2(q3.y), w3, a2[1]);
        a2[2] = __hfma2(u2h2(q3.z), w3, a2[2]);
        a2[3] = __hfma2(u2h2(q3.w), w3, a2[3]);
      }
      *reinterpret_cast<uint4*>(&vals[pl * 72 + chg * 8]) =
          uint4{h22u(a2[0]), h22u(a2[1]), h22u(a2[2]), h22u(a2[3])};
    }
    __syncthreads();
    // ---- MFMA: C[co][pos] += W[co][cin] * V[cin][pos]; A from L2, B from LDS
    {
      const unsigned short* wk = wTb + (size_t)k * 4096;
#pragma unroll
      for (int s = 0; s < 2; ++s) {
        half8 bfr = *reinterpret_cast<const half8*>(
            &vals[(wv * 16 + (lane & 15)) * 72 + s * 32 + (lane >> 4) * 8]);
#pragma unroll
        for (int mt = 0; mt < 4; ++mt) {
          half8 afr = *reinterpret_cast<const half8*>(
              wk + mt * 1024 + s * 512 + (lane & 15) * 32 + (lane >> 4) * 8);
          acc[mt] = __builtin_amdgcn_mfma_f32_16x16x32_f16(afr, bfr, acc[mt], 0, 0, 0);
        }
      }
    }
    __syncthreads();
  }

  // part[kc][b][tile][co][pos]; co = mt*16+(lane>>4)*4+reg, pos = wv*16+(lane&15)
  float* pp = part + ((size_t)(kc * 2 + b) * NTILE + tile) * 4096;
#pragma unroll
  for (int mt = 0; mt < 4; ++mt) {
#pragma unroll
    for (int reg = 0; reg < 4; ++reg) {
      int co = mt * 16 + (lane >> 4) * 4 + reg;
      pp[co * 64 + wv * 16 + (lane & 15)] = acc[mt][reg];
    }
  }
}

// out[b][co][p] = bias[co] + sum_kc part[kc][b][tile][co][pos]  (float4)
__global__ __launch_bounds__(256) void k_red(const float* __restrict__ part,
                                             const float* __restrict__ bias,
                                             float* __restrict__ out) {
  int i = blockIdx.x * 256 + threadIdx.x;  // 589,824 float4 units
  int p4 = i % (SP / 4);
  int co = (i / (SP / 4)) & 63;
  int b = i / ((SP / 4) * 64);
  int p = p4 * 4;
  int tile = p >> 6, pos = p & 63;
  size_t base = ((size_t)b * NTILE + tile) * 4096 + co * 64 + pos;
  float4 s = *reinterpret_cast<const float4*>(&part[base]);
#pragma unroll
  for (int kc = 1; kc < KC; ++kc) {
    float4 v = *reinterpret_cast<const float4*>(&part[base + (size_t)kc * (2 * NTILE * 4096)]);
    s.x += v.x; s.y += v.y; s.z += v.z; s.w += v.w;
  }
  float bb = bias[co];
  s.x += bb; s.y += bb; s.z += bb; s.w += bb;
  *reinterpret_cast<float4*>(&out[((size_t)(b * 64 + co)) * SP + p]) = s;
}

extern "C" void kernel_launch(void* const* d_in, const int* in_sizes, int n_in,
                              void* d_out, int out_size, void* d_ws, size_t ws_size,
                              hipStream_t stream) {
  const float* x = (const float*)d_in[0];
  const float* cw = (const float*)d_in[1];
  const float* cb = (const float*)d_in[2];
  const float* w = (const float*)d_in[3];
  const float* bias = (const float*)d_in[4];
  float* out = (float*)d_out;

  char* ws = (char*)d_ws;
  float* off = (float*)ws;                                   // 11,943,936 B
  unsigned short* xTh = (unsigned short*)(ws + 11943936);    //  4,718,592 B
  unsigned short* wTb = (unsigned short*)(ws + 16662528);    //    221,184 B
  unsigned short* wq = (unsigned short*)(ws + 16883712);     //    331,776 B
  float* part = (float*)(ws + 17215488);                     // KC*9,437,184 = 28,311,552 B
  float* opart = (float*)(ws + 45527040);                    // CS*11,943,936 = 23,887,872 B

  hipLaunchKernelGGL(k_xTh, dim3(9216), dim3(256), 0, stream, x, xTh);
  hipLaunchKernelGGL(k_wTb, dim3(432), dim3(256), 0, stream, w, wTb);
  hipLaunchKernelGGL(k_offwq, dim3(648), dim3(256), 0, stream, cw, wq);
  hipLaunchKernelGGL(k_offm3, dim3(CS * 576), dim3(256), 0, stream, xTh, wq, opart);
  hipLaunchKernelGGL(k_offred, dim3(2916), dim3(256), 0, stream, opart, cb, off);
  hipLaunchKernelGGL(k_mainp, dim3(KC * 576), dim3(256), 0, stream, xTh, off, wTb, part);
  hipLaunchKernelGGL(k_red, dim3(2304), dim3(256), 0, stream, part, bias, out);
}